// Round 9
// baseline (308.502 us; speedup 1.0000x reference)
//
#include <hip/hip_runtime.h>

typedef unsigned short ushort_t;
typedef __bf16 bf16x8 __attribute__((ext_vector_type(8)));
typedef float f32x4 __attribute__((ext_vector_type(4)));

__device__ __forceinline__ ushort_t f2b(float f) {
  union { float f; unsigned u; } v; v.f = f;
  unsigned r = v.u + 0x7FFFu + ((v.u >> 16) & 1u);
  return (ushort_t)(r >> 16);
}
__device__ __forceinline__ float b2f(ushort_t u) {
  union { unsigned u; float f; } v; v.u = ((unsigned)u) << 16;
  return v.f;
}
__device__ __forceinline__ f32x4 MFMA(bf16x8 a, bf16x8 b, f32x4 c) {
  return __builtin_amdgcn_mfma_f32_16x16x32_bf16(a, b, c, 0, 0, 0);
}
// async global->LDS, 16 B per lane; lds base must be wave-uniform
__device__ __forceinline__ void gload_lds16(const ushort_t* g, ushort_t* l) {
  __builtin_amdgcn_global_load_lds(
      (const __attribute__((address_space(1))) unsigned int*)g,
      (__attribute__((address_space(3))) unsigned int*)l, 16, 0, 0);
}

// ------- conv1_w (256,64,3,3) -> w1t2 FRAGMENT-MAJOR bf16 -------
// w1t2[(s*16+g)*512 + lane*8 + j] = w1[n=g*16+(lane&15)][c=(s&1)*32+((lane>>4)<<3)+j][tap=s>>1]
__global__ void cast_w1t_kernel(const float* __restrict__ w1, ushort_t* __restrict__ w1t2) {
  int i = blockIdx.x * 256 + threadIdx.x;   // 147456 total
  int tap = i / 16384;
  int rem = i & 16383;
  int nn = rem >> 6, c = rem & 63;
  int g = nn >> 4, l15v = nn & 15;
  int kk = c >> 5, lg = (c >> 3) & 3, j = c & 7;
  int lanev = lg * 16 + l15v;
  w1t2[((tap * 2 + kk) * 16 + g) * 512 + lanev * 8 + j] = f2b(w1[(nn * 64 + c) * 9 + tap]);
}

// ---------------- generic f32 -> bf16 cast ----------------
__global__ void cast_f32_bf16_kernel(const float* __restrict__ src, ushort_t* __restrict__ dst, int n) {
  for (int i = blockIdx.x * blockDim.x + threadIdx.x; i < n; i += gridDim.x * blockDim.x)
    dst[i] = f2b(src[i]);
}

// ------- w_poly cast, PRE-SWIZZLED per row: col -> col ^ ((row&7)<<3) -------
__global__ void cast_wp_kernel(const float* __restrict__ src, ushort_t* __restrict__ dst) {
  for (int i = blockIdx.x * blockDim.x + threadIdx.x; i < 4227072; i += gridDim.x * blockDim.x) {
    int row = i / 8256;
    int col = i - row * 8256;
    dst[row * 8256 + (col ^ ((row & 7) << 3))] = f2b(src[i]);
  }
}

// ---------------- prep: gather wh_pred, init_polys, points, out[0] ----------------
__global__ void prep_kernel(const float* __restrict__ wh, const int* __restrict__ ct_ind,
                            const int* __restrict__ ct_b, float* __restrict__ out,
                            float* __restrict__ pts) {
  int n = blockIdx.x, t = threadIdx.x;      // 2000 x 128
  int ci = ct_ind[n];
  int b = ct_b[n];
  int ctx = ci & 255;
  int cty = (ci >> 8) & 255;
  float fx = (float)ctx, fy = (float)cty;
  size_t base = ((size_t)b * 256 + 2 * t) * 65536 + (size_t)cty * 256 + ctx;
  float ox = wh[base];
  float oy = wh[base + 65536];
  float ix = ox * 10.f + fx, iy = oy * 10.f + fy;
  out[(n * 128 + t) * 2]     = ix * 4.f;
  out[(n * 128 + t) * 2 + 1] = iy * 4.f;
  float* pn = pts + (size_t)n * 258;
  if (t == 0) { pn[0] = fx; pn[1] = fy; }
  pn[2 + t * 2] = ix;
  pn[3 + t * 2] = iy;
}

// ---------------- fused cast + conv1(3x3)+bias+relu + conv2(1x1)+bias -> f2 -------
// Reads x (f32 NCHW) DIRECTLY: 2-stage LDS transpose builds the swizzled bf16 strip
// in-kernel (no xt tensor). MFMA core + epilogue identical to the R7 kernel:
// wave-tile 64px x 128ch, B (weights) from global w1t2 into regs, no main-loop barriers.
__global__ __launch_bounds__(512, 2)
void conv_fused_kernel(const float* __restrict__ x, const ushort_t* __restrict__ w1t2,
                       const float* __restrict__ b1, const float* __restrict__ w2,
                       const float* __restrict__ b2, ushort_t* __restrict__ f2) {
  __shared__ __align__(16) char smem[163840];
  ushort_t* strip = (ushort_t*)smem;              // [4][136][64] bf16 = 69632 B
  float*    tile2 = (float*)(smem + 69632);       // [2][64][137] f32 = 70144 B
  ushort_t* F1    = (ushort_t*)smem;              // [256][256] = 131072 (epilogue)
  ushort_t* W2l   = (ushort_t*)(smem + 131072);   // [64][256] = 32768 (epilogue)
  ushort_t* T     = (ushort_t*)smem;              // [256][64] (store stage)

  int rawblk = blockIdx.x;                         // 1024
  int blk = ((rawblk & 7) << 7) + (rawblk >> 3);   // bijective XCD swizzle (1024%8==0)
  int b = blk >> 8;
  int rest = blk & 255;
  int y2 = (rest >> 1) << 1;                       // first output row (even)
  int x0 = (rest & 1) << 7;                        // 0 or 128
  int tid = threadIdx.x;
  int wid = tid >> 6, lane = tid & 63;
  int l15 = lane & 15, lg = lane >> 4;
  int wm = (wid >> 1) << 6;    // px offset: 0,64,128,192 (px p: row=p>>7, col=p&127)
  int wn = (wid & 1) << 7;     // ch offset: 0,128
  int g0 = wn >> 4;            // weight fragment group base: 0 or 8

  // prefetch B for step 0 into regs (8 frags, 1024 B lines, L2-resident)
  bf16x8 Breg[2][8];
#pragma unroll
  for (int nf = 0; nf < 8; ++nf)
    Breg[0][nf] = *(const bf16x8*)(w1t2 + (size_t)(g0 + nf) * 512 + lane * 8);

  // ---- build strip (4 rows: src rows y2-1..y2+2, src cols x0-1..x0+134) ----
  const float* xb = x + (size_t)b * 4194304;       // [64][256][256]
#pragma unroll
  for (int st = 0; st < 2; ++st) {
    // stage A: coalesced f32 loads -> tile2[2][64][137]
#pragma unroll
    for (int it = 0; it < 34; ++it) {
      int u = it * 512 + tid;                      // 0..17407
      int rr = u / 8704;
      int rem = u - rr * 8704;
      int c = rem / 136, tp = rem - c * 136;
      int ys = y2 + st * 2 + rr - 1;
      int xs = x0 + tp - 1;
      float v = 0.f;
      if (ys >= 0 && ys < 256 && xs >= 0 && xs < 256)
        v = xb[(size_t)c * 65536 + ys * 256 + xs];
      tile2[(rr * 64 + c) * 137 + tp] = v;
    }
    __syncthreads();
    // stage B: transpose-read 8-ch octets, pack bf16, swizzled b128 strip write
#pragma unroll
    for (int it = 0; it < 5; ++it) {
      int u = it * 512 + tid;                      // 2176 units
      if (u < 2176) {
        int rr = u / 1088;
        int rem = u - rr * 1088;
        int tp = rem >> 3, oc = rem & 7;
        union { ushort_t s[8]; uint4 v4; } pk;
#pragma unroll
        for (int j = 0; j < 8; ++j)
          pk.s[j] = f2b(tile2[(rr * 64 + oc * 8 + j) * 137 + tp]);
        int ry = st * 2 + rr;
        *(uint4*)(strip + ((ry * 136 + tp) << 6) + ((oc << 3) ^ ((tp & 7) << 3))) = pk.v4;
      }
    }
    __syncthreads();
  }

  f32x4 acc[4][8] = {};

#pragma unroll
  for (int s = 0; s < 18; ++s) {       // s = tap*2 + kk
    const int tap = s >> 1, kk = s & 1;
    const int cur = s & 1;
    if (s < 17) {                      // prefetch next step's weights (L2-hit)
#pragma unroll
      for (int nf = 0; nf < 8; ++nf)
        Breg[cur ^ 1][nf] = *(const bf16x8*)(w1t2 + (size_t)((s + 1) * 16 + g0 + nf) * 512 + lane * 8);
    }
    const int dy = tap / 3 - 1, dx = tap % 3 - 1;
    const int sr  = (wm >> 7) + dy + 1;      // strip row (wave-uniform)
    const int spb = (wm & 127) + dx + 1;     // strip px base
    const int c0 = (kk << 5) + (lg << 3);
    bf16x8 a[4];
#pragma unroll
    for (int m = 0; m < 4; ++m) {
      int sp = spb + m * 16 + l15;
      a[m] = *(const bf16x8*)(strip + ((sr * 136 + sp) << 6) + (c0 ^ ((sp & 7) << 3)));
    }
#pragma unroll
    for (int nf = 0; nf < 8; ++nf)
#pragma unroll
      for (int m = 0; m < 4; ++m)
        acc[m][nf] = MFMA(a[m], Breg[cur][nf], acc[m][nf]);
  }
  __syncthreads();                     // all strip reads done; F1 may overwrite

  // conv1 epilogue: relu(acc + b1) -> F1 px-major, XOR-swizzled on ch by (p&7)
#pragma unroll
  for (int nf = 0; nf < 8; ++nf) {
    int ch = wn + nf * 16 + l15;
    float bias = b1[ch];
#pragma unroll
    for (int m = 0; m < 4; ++m) {
#pragma unroll
      for (int r = 0; r < 4; ++r) {
        int p = wm + m * 16 + lg * 4 + r;
        F1[(p << 8) + (ch ^ ((p & 7) << 3))] = f2b(fmaxf(acc[m][nf][r] + bias, 0.f));
      }
    }
  }
  // stage w2 (64 oc x 256 ic) -> W2l swizzled on ic by (oc&7)
#pragma unroll
  for (int it = 0; it < 4; ++it) {
    int u = it * 512 + tid;            // 2048 octets
    int oc = u >> 5, ic = (u & 31) << 3;
    float4 fa = *(const float4*)(w2 + (oc << 8) + ic);
    float4 fb = *(const float4*)(w2 + (oc << 8) + ic + 4);
    union { ushort_t s[8]; uint4 v; } pk;
    pk.s[0] = f2b(fa.x); pk.s[1] = f2b(fa.y); pk.s[2] = f2b(fa.z); pk.s[3] = f2b(fa.w);
    pk.s[4] = f2b(fb.x); pk.s[5] = f2b(fb.y); pk.s[6] = f2b(fb.z); pk.s[7] = f2b(fb.w);
    *(uint4*)(W2l + (oc << 8) + (ic ^ ((oc & 7) << 3))) = pk.v;
  }
  __syncthreads();
  // conv2: O[256 px][64 oc] = F1 @ W2^T; wave owns 32 px
  int wpx = wid << 5;
  f32x4 acc2[2][4] = {};
#pragma unroll
  for (int kc = 0; kc < 8; ++kc) {
    int c0 = (kc << 5) + (lg << 3);
    bf16x8 a2[2];
#pragma unroll
    for (int mm = 0; mm < 2; ++mm) {
      int p = wpx + mm * 16 + l15;
      a2[mm] = *(const bf16x8*)(F1 + (p << 8) + (c0 ^ ((p & 7) << 3)));
    }
#pragma unroll
    for (int nf = 0; nf < 4; ++nf) {
      int oc = nf * 16 + l15;
      bf16x8 bw = *(const bf16x8*)(W2l + (oc << 8) + (c0 ^ ((oc & 7) << 3)));
#pragma unroll
      for (int mm = 0; mm < 2; ++mm)
        acc2[mm][nf] = MFMA(a2[mm], bw, acc2[mm][nf]);
    }
  }
  __syncthreads();                     // all F1 reads done; T may overwrite
#pragma unroll
  for (int mm = 0; mm < 2; ++mm)
#pragma unroll
    for (int nf = 0; nf < 4; ++nf) {
      int oc = nf * 16 + l15;
      float bias = b2[oc];
#pragma unroll
      for (int r = 0; r < 4; ++r) {
        int p = wpx + mm * 16 + lg * 4 + r;
        T[(p << 6) + (oc ^ ((p & 7) << 3))] = f2b(acc2[mm][nf][r] + bias);
      }
    }
  __syncthreads();
  const size_t imgbase = (size_t)b * 65536;
#pragma unroll
  for (int it = 0; it < 4; ++it) {
    int u = it * 512 + tid;            // 2048 octets
    int p = u >> 3, co = (u & 7) << 3;
    uint4 v = *(const uint4*)(T + (p << 6) + (co ^ ((p & 7) << 3)));
    int gpx = (y2 + (p >> 7)) * 256 + x0 + (p & 127);
    *(uint4*)(f2 + (imgbase + gpx) * 64 + co) = v;
  }
}

// ---------------- bilinear sample -> fp[n][col ^ swz(n)] bf16 (PRE-SWIZZLED) ------
__global__ void sample_kernel(const ushort_t* __restrict__ f2, const float* __restrict__ pts,
                              const int* __restrict__ ct_b, ushort_t* __restrict__ fp) {
  int n = blockIdx.x, t = threadIdx.x;   // 2000 x 128
  __shared__ float pl[258];
  __shared__ __align__(16) ushort_t fpl[8256];   // [64][129]
  int b = ct_b[n];
  const ushort_t* fb = f2 + (size_t)b * 4194304;
  for (int i = t; i < 258; i += 128) pl[i] = pts[(size_t)n * 258 + i];
  __syncthreads();
  int c4 = t & 15;            // channel quad: ch = 4*c4 .. 4*c4+3
  int ps = t >> 4;            // 0..7 point slot
  for (int base = 0; base < 136; base += 8) {
    int pt = base + ps;
    bool live = pt < 129;
    int ptc = live ? pt : 0;
    float px = pl[ptc * 2], py = pl[ptc * 2 + 1];
    float sx = px - 0.5f, sy = py - 0.5f;
    float fx0 = floorf(sx), fy0 = floorf(sy);
    int x0 = (int)fx0, y0 = (int)fy0;
    float wx1 = sx - fx0, wy1 = sy - fy0;
    float wx0 = 1.f - wx1, wy0 = 1.f - wy1;
    float a0 = 0.f, a1 = 0.f, a2 = 0.f, a3 = 0.f;
#pragma unroll
    for (int cy = 0; cy < 2; ++cy) {
#pragma unroll
      for (int cx = 0; cx < 2; ++cx) {
        int yc = y0 + cy, xc = x0 + cx;
        float w = (cy ? wy1 : wy0) * (cx ? wx1 : wx0);
        bool valid = (xc >= 0) && (xc < 256) && (yc >= 0) && (yc < 256);
        int ycc = min(max(yc, 0), 255), xcc = min(max(xc, 0), 255);
        uint2 v = *(const uint2*)(fb + ((size_t)(ycc * 256 + xcc)) * 64 + (c4 << 2));
        float ww = valid ? w : 0.f;
        a0 += b2f((ushort_t)(v.x & 0xFFFF)) * ww;
        a1 += b2f((ushort_t)(v.x >> 16)) * ww;
        a2 += b2f((ushort_t)(v.y & 0xFFFF)) * ww;
        a3 += b2f((ushort_t)(v.y >> 16)) * ww;
      }
    }
    if (live) {
      int ch = c4 << 2;
      fpl[(ch + 0) * 129 + pt] = f2b(a0);
      fpl[(ch + 1) * 129 + pt] = f2b(a1);
      fpl[(ch + 2) * 129 + pt] = f2b(a2);
      fpl[(ch + 3) * 129 + pt] = f2b(a3);
    }
  }
  __syncthreads();
  uint4* fo = (uint4*)(fp + (size_t)n * 8256);
  const uint4* fi = (const uint4*)fpl;
  int key = n & 7;
  for (int i = t; i < 1032; i += 128) fo[i ^ key] = fi[i];
}

// ---------------- split-K GEMM1: 128x128 tiles, partials[kc][2048][512] f32 -------
__global__ __launch_bounds__(256)
void gemm_splitk_kernel(const ushort_t* __restrict__ A, const ushort_t* __restrict__ B,
                        float* __restrict__ partials) {
  __shared__ __align__(16) ushort_t Al[8192];   // [128][64] swizzled
  __shared__ __align__(16) ushort_t Bl[8192];
  int spatial = blockIdx.x;                      // 64
  int kc = blockIdx.y;                           // 8
  int n_t = (spatial & 7) >> 1;                  // 0..3 (XCD-locked)
  int m_t = ((spatial >> 3) << 1) | (spatial & 1);   // 0..15
  int m0 = m_t << 7, n0 = n_t << 7;
  int ks0 = (129 * kc) >> 3, ks1 = (129 * (kc + 1)) >> 3;   // 64-wide k-steps

  int tid = threadIdx.x;
  int wid = tid >> 6, lane = tid & 63;
  int l15 = lane & 15, lg = lane >> 4;
  int wm = (wid >> 1) << 6, wn = (wid & 1) << 6;
  int srow = (lane >> 3);                        // stage row-in-octet
  int soct = lane & 7;
  f32x4 acc[4][4] = {};
  for (int ks = ks0; ks < ks1; ++ks) {
    __syncthreads();
#pragma unroll
    for (int j = 0; j < 4; ++j) {
      int q = (wid << 2) + j;                    // 16 chunks of 1024 B
      int r = (q << 3) + srow;                   // tile row 0..127
      int ar = m0 + r;
      if (ar >= 2000) ar = 1992 + (ar & 7);      // clamp, swizzle-key preserved
      gload_lds16(A + (size_t)ar * 8256 + ks * 64 + soct * 8, Al + q * 512);
      gload_lds16(B + (size_t)(n0 + r) * 8256 + ks * 64 + soct * 8, Bl + q * 512);
    }
    __syncthreads();
#pragma unroll
    for (int kk = 0; kk < 2; ++kk) {
      int c0 = (kk << 5) + (lg << 3);
      bf16x8 a[4], b[4];
#pragma unroll
      for (int m = 0; m < 4; ++m) {
        int row = wm + m * 16 + l15;
        a[m] = *(const bf16x8*)(Al + (row << 6) + (c0 ^ ((row & 7) << 3)));
      }
#pragma unroll
      for (int nf = 0; nf < 4; ++nf) {
        int row = wn + nf * 16 + l15;
        b[nf] = *(const bf16x8*)(Bl + (row << 6) + (c0 ^ ((row & 7) << 3)));
      }
#pragma unroll
      for (int m = 0; m < 4; ++m)
#pragma unroll
        for (int nf = 0; nf < 4; ++nf)
          acc[m][nf] = MFMA(a[m], b[nf], acc[m][nf]);
    }
  }
  float* pout = partials + (size_t)kc * 1048576;   // 2048*512
#pragma unroll
  for (int m = 0; m < 4; ++m)
#pragma unroll
    for (int nf = 0; nf < 4; ++nf)
#pragma unroll
      for (int r = 0; r < 4; ++r) {
        int row = m0 + wm + m * 16 + lg * 4 + r;
        int col = n0 + wn + nf * 16 + l15;
        pout[(size_t)row * 512 + col] = acc[m][nf][r];
      }
}

// ---------------- reduce 8 partials -> off1 bf16 [2048][512] ----------------
__global__ void reduce_splitk_kernel(const float* __restrict__ partials,
                                     ushort_t* __restrict__ off1) {
  int i = blockIdx.x * 256 + threadIdx.x;    // 262144 threads x 4 elems
  size_t idx = (size_t)i * 4;
  float4 s = *(const float4*)(partials + idx);
#pragma unroll
  for (int c = 1; c < 8; ++c) {
    float4 p = *(const float4*)(partials + (size_t)c * 1048576 + idx);
    s.x += p.x; s.y += p.y; s.z += p.z; s.w += p.w;
  }
  union { ushort_t u[4]; uint2 v; } pk;
  pk.u[0] = f2b(s.x); pk.u[1] = f2b(s.y); pk.u[2] = f2b(s.z); pk.u[3] = f2b(s.w);
  *(uint2*)(off1 + idx) = pk.v;
}

// ---------------- GEMM2: off1 @ wfb^T + bias -> out (64x64 tiles) ----------------
__global__ __launch_bounds__(256)
void gemm64_epi_kernel(const ushort_t* __restrict__ A, const ushort_t* __restrict__ B,
                       const float* __restrict__ bias, const float* __restrict__ out0,
                       float* __restrict__ out1, int Mvalid) {
  __shared__ ushort_t Alds[64][72];
  __shared__ ushort_t Blds[64][72];
  const int K = 512;
  int n0 = blockIdx.x * 64, m0 = blockIdx.y * 64;
  int tid = threadIdx.x;
  int wid = tid >> 6, lane = tid & 63;
  int l15 = lane & 15, lg = lane >> 4;
  int wm = (wid >> 1) * 32, wn = (wid & 1) * 32;
  f32x4 acc[2][2] = {};
  for (int ks = 0; ks < K / 64; ++ks) {
    __syncthreads();
#pragma unroll
    for (int it = 0; it < 2; ++it) {
      int u = it * 256 + tid;
      int r = u >> 3, cc = (u & 7) << 3;
      *(uint4*)(&Alds[r][cc]) = *(const uint4*)(A + (size_t)(m0 + r) * K + ks * 64 + cc);
      *(uint4*)(&Blds[r][cc]) = *(const uint4*)(B + (size_t)(n0 + r) * K + ks * 64 + cc);
    }
    __syncthreads();
#pragma unroll
    for (int kk = 0; kk < 2; ++kk) {
      int c0 = (kk << 5) + (lg << 3);
      bf16x8 a[2], b[2];
      a[0] = *(const bf16x8*)(&Alds[wm + l15][c0]);
      a[1] = *(const bf16x8*)(&Alds[wm + 16 + l15][c0]);
      b[0] = *(const bf16x8*)(&Blds[wn + l15][c0]);
      b[1] = *(const bf16x8*)(&Blds[wn + 16 + l15][c0]);
#pragma unroll
      for (int m = 0; m < 2; ++m)
#pragma unroll
        for (int nf = 0; nf < 2; ++nf)
          acc[m][nf] = MFMA(a[m], b[nf], acc[m][nf]);
    }
  }
#pragma unroll
  for (int m = 0; m < 2; ++m)
#pragma unroll
    for (int nf = 0; nf < 2; ++nf)
#pragma unroll
      for (int r = 0; r < 4; ++r) {
        int row = m0 + wm + m * 16 + lg * 4 + r;
        int col = n0 + wn + nf * 16 + l15;
        if (row < Mvalid) {
          float v = acc[m][nf][r] + bias[col];
          out1[(size_t)row * 256 + col] = v * 16.f + out0[(size_t)row * 256 + col];
        }
      }
}

// ---------------- launch ----------------
extern "C" void kernel_launch(void* const* d_in, const int* in_sizes, int n_in,
                              void* d_out, int out_size, void* d_ws, size_t ws_size,
                              hipStream_t stream) {
  const float* x    = (const float*)d_in[0];
  const float* wh   = (const float*)d_in[1];
  const int* ct_ind = (const int*)d_in[2];
  const int* ct_b   = (const int*)d_in[3];
  const float* w1   = (const float*)d_in[4];
  const float* b1   = (const float*)d_in[5];
  const float* w2   = (const float*)d_in[6];
  const float* b2   = (const float*)d_in[7];
  const float* wp   = (const float*)d_in[8];
  const float* wf   = (const float*)d_in[9];
  const float* bfu  = (const float*)d_in[10];
  float* out = (float*)d_out;
  char* ws = (char*)d_ws;

  // ws map (bytes): (xt eliminated; partials owns ws+0)
  float* partials = (float*)(ws + 0);               // 33,554,432
  ushort_t* w1t2  = (ushort_t*)(ws + 34080768);     //    294,912
  ushort_t* f2    = (ushort_t*)(ws + 34375680);     // 33,554,432
  ushort_t* wpb   = (ushort_t*)(ws + 67930112);     //  8,454,144
  ushort_t* wfb   = (ushort_t*)(ws + 76384256);     //    262,144
  ushort_t* fp    = (ushort_t*)(ws + 76646400);     // 33,024,000 (2000 rows, swizzled)
  ushort_t* off1  = (ushort_t*)(ws + 109670400);    //  2,097,152 (2048x512)
  float*    pts   = (float*)(ws + 111767552);       //  2,064,000  (end 113,831,552)

  cast_w1t_kernel<<<dim3(576), dim3(256), 0, stream>>>(w1, w1t2);
  cast_wp_kernel<<<dim3(2064), dim3(256), 0, stream>>>(wp, wpb);
  cast_f32_bf16_kernel<<<dim3(64), dim3(256), 0, stream>>>(wf, wfb, 131072);
  prep_kernel<<<dim3(2000), dim3(128), 0, stream>>>(wh, ct_ind, ct_b, out, pts);
  conv_fused_kernel<<<dim3(1024), dim3(512), 0, stream>>>(x, w1t2, b1, w2, b2, f2);
  sample_kernel<<<dim3(2000), dim3(128), 0, stream>>>(f2, pts, ct_b, fp);
  gemm_splitk_kernel<<<dim3(64, 8), dim3(256), 0, stream>>>(fp, wpb, partials);
  reduce_splitk_kernel<<<dim3(1024), dim3(256), 0, stream>>>(partials, off1);
  gemm64_epi_kernel<<<dim3(4, 32), dim3(256), 0, stream>>>(off1, wfb, bfu, out,
                                                           out + 512000, 2000);
}

// Round 10
// 221.393 us; speedup vs baseline: 1.3935x; 1.3935x over previous
//
#include <hip/hip_runtime.h>

typedef unsigned short ushort_t;
typedef __bf16 bf16x8 __attribute__((ext_vector_type(8)));
typedef float f32x4 __attribute__((ext_vector_type(4)));

__device__ __forceinline__ ushort_t f2b(float f) {
  union { float f; unsigned u; } v; v.f = f;
  unsigned r = v.u + 0x7FFFu + ((v.u >> 16) & 1u);
  return (ushort_t)(r >> 16);
}
__device__ __forceinline__ float b2f(ushort_t u) {
  union { unsigned u; float f; } v; v.u = ((unsigned)u) << 16;
  return v.f;
}
__device__ __forceinline__ f32x4 MFMA(bf16x8 a, bf16x8 b, f32x4 c) {
  return __builtin_amdgcn_mfma_f32_16x16x32_bf16(a, b, c, 0, 0, 0);
}
// async global->LDS, 16 B per lane; lds base must be wave-uniform
__device__ __forceinline__ void gload_lds16(const ushort_t* g, ushort_t* l) {
  __builtin_amdgcn_global_load_lds(
      (const __attribute__((address_space(1))) unsigned int*)g,
      (__attribute__((address_space(3))) unsigned int*)l, 16, 0, 0);
}

// xt_pad geometry: [4][258 rows][258 cols][64 ch] bf16, 1-px zero border,
// channel octet stored at slot c ^ ((col&7)<<3)  (pre-swizzled for LDS)
#define XTW 258

// ---------------- zero the xt_pad border (rows 0,257; cols 0,257) ----------------
__global__ void zero_border_kernel(ushort_t* __restrict__ xt) {
  int i = blockIdx.x * 256 + threadIdx.x;   // 32896 uint4 writes
  if (i >= 32896) return;
  int px_id = i >> 3, oct = (i & 7) << 3;
  int img = px_id / 1028, r = px_id - img * 1028;
  int row, col;
  if (r < 516) { row = (r < 258) ? 0 : 257; col = (r < 258) ? r : r - 258; }
  else { int rr = r - 516; row = 1 + (rr >> 1); col = (rr & 1) ? 257 : 0; }
  uint4 z = make_uint4(0, 0, 0, 0);
  *(uint4*)(xt + (((size_t)img * XTW + row) * XTW + col) * 64 + oct) = z;
}

// ---------------- cast cnn_feature NCHW f32 -> padded+swizzled NHWC bf16 ----------
__global__ void cast_xt_kernel(const float* __restrict__ x, ushort_t* __restrict__ xt) {
  __shared__ float tile[64][65];
  int blk = blockIdx.x;               // 4096 = 4 images * 1024 tiles (64 px each)
  int b = blk >> 10, rest = blk & 1023;
  int y = rest >> 2, xseg = (rest & 3) << 6;
  int p0 = y * 256 + xseg;
  int t = threadIdx.x;                // 256
#pragma unroll
  for (int rep = 0; rep < 16; ++rep) {
    int lin = rep * 256 + t;
    int c = lin >> 6, p = lin & 63;
    tile[c][p] = x[((size_t)(b * 64 + c)) * 65536 + p0 + p];
  }
  __syncthreads();
#pragma unroll
  for (int rep = 0; rep < 2; ++rep) {
    int u = rep * 256 + t;            // 512 units of 8ch
    int p = u >> 3, cc = (u & 7) << 3;
    union { ushort_t s[8]; uint4 v; } pk;
#pragma unroll
    for (int j = 0; j < 8; ++j) pk.s[j] = f2b(tile[cc + j][p]);
    int gx = xseg + p + 1;
    size_t base = (((size_t)b * XTW + (y + 1)) * XTW + gx) * 64;
    *(uint4*)(xt + base + (cc ^ ((gx & 7) << 3))) = pk.v;
  }
}

// ------- conv1_w (256,64,3,3) -> w1t[tap][n][c^swz(n)] bf16 (PRE-SWIZZLED) -------
__global__ void cast_w1t_kernel(const float* __restrict__ w1, ushort_t* __restrict__ w1t) {
  int i = blockIdx.x * 256 + threadIdx.x;   // 147456 total
  int tap = i >> 14;
  int rem = i & 16383;
  int nn = rem >> 6, c = rem & 63;
  int cs = c ^ ((nn & 7) << 3);
  w1t[tap * 16384 + nn * 64 + cs] = f2b(w1[(nn * 64 + c) * 9 + tap]);
}

// ---------------- generic f32 -> bf16 cast ----------------
__global__ void cast_f32_bf16_kernel(const float* __restrict__ src, ushort_t* __restrict__ dst, int n) {
  for (int i = blockIdx.x * blockDim.x + threadIdx.x; i < n; i += gridDim.x * blockDim.x)
    dst[i] = f2b(src[i]);
}

// ------- w_poly cast, PRE-SWIZZLED per row: col -> col ^ ((row&7)<<3) -------
__global__ void cast_wp_kernel(const float* __restrict__ src, ushort_t* __restrict__ dst) {
  for (int i = blockIdx.x * blockDim.x + threadIdx.x; i < 4227072; i += gridDim.x * blockDim.x) {
    int row = i / 8256;
    int col = i - row * 8256;
    dst[row * 8256 + (col ^ ((row & 7) << 3))] = f2b(src[i]);
  }
}

// ---------------- prep: gather wh_pred, init_polys, points, out[0] ----------------
__global__ void prep_kernel(const float* __restrict__ wh, const int* __restrict__ ct_ind,
                            const int* __restrict__ ct_b, float* __restrict__ out,
                            float* __restrict__ pts) {
  int n = blockIdx.x, t = threadIdx.x;      // 2000 x 128
  int ci = ct_ind[n];
  int b = ct_b[n];
  int ctx = ci & 255;
  int cty = (ci >> 8) & 255;
  float fx = (float)ctx, fy = (float)cty;
  size_t base = ((size_t)b * 256 + 2 * t) * 65536 + (size_t)cty * 256 + ctx;
  float ox = wh[base];
  float oy = wh[base + 65536];
  float ix = ox * 10.f + fx, iy = oy * 10.f + fy;
  out[(n * 128 + t) * 2]     = ix * 4.f;
  out[(n * 128 + t) * 2 + 1] = iy * 4.f;
  float* pn = pts + (size_t)n * 258;
  if (t == 0) { pn[0] = fx; pn[1] = fy; }
  pn[2 + t * 2] = ix;
  pn[3 + t * 2] = iy;
}

// ---------------- fused conv1(3x3)+bias+relu + conv2(1x1)+bias -> f2 NHWC bf16 ----
// 2-row blocks: M=256 px (2 rows x 128), N=256 ch, 8 waves, wave-tile 64x128.
// 4-row strip staged once via async gload_lds; 2-deep LDS weight buffers.
// (The best-measured conv variant: R5-submission, ~70 us.)
__global__ __launch_bounds__(512, 1)
void conv_fused_kernel(const ushort_t* __restrict__ xt, const ushort_t* __restrict__ w1t,
                       const float* __restrict__ b1, const float* __restrict__ w2,
                       const float* __restrict__ b2, ushort_t* __restrict__ f2) {
  __shared__ __align__(16) char smem[163840];
  ushort_t* strip = (ushort_t*)smem;              // [4][136][64] = 69632 B
  ushort_t* Bb0   = (ushort_t*)(smem + 69632);    // [256][64] = 32768 B
  ushort_t* Bb1   = (ushort_t*)(smem + 102400);   // ends 135168
  ushort_t* F1    = (ushort_t*)smem;              // [256][256] = 131072 (epilogue)
  ushort_t* W2l   = (ushort_t*)(smem + 131072);   // [64][256] = 32768 (epilogue)
  ushort_t* T     = (ushort_t*)smem;              // [256][64] (store stage)

  int rawblk = blockIdx.x;                         // 1024
  int blk = ((rawblk & 7) << 7) + (rawblk >> 3);   // bijective XCD swizzle (1024%8==0)
  int b = blk >> 8;
  int rest = blk & 255;
  int y2 = (rest >> 1) << 1;                       // first output row (even)
  int x0 = (rest & 1) << 7;                        // 0 or 128
  int tid = threadIdx.x;
  int wid = tid >> 6, lane = tid & 63;
  int l15 = lane & 15, lg = lane >> 4;
  int wm = (wid >> 1) << 6;    // px offset: 0,64,128,192
  int wn = (wid & 1) << 7;     // ch offset: 0,128

  // prologue: issue weight pf for taps 0,1 (linear dest = pre-swizzled layout)
#pragma unroll
  for (int j = 0; j < 4; ++j) {
    int q = (wid << 2) + j;            // 32 chunks of 1024 B
    gload_lds16(w1t + q * 512 + lane * 8, Bb0 + q * 512);
  }
#pragma unroll
  for (int j = 0; j < 4; ++j) {
    int q = (wid << 2) + j;
    gload_lds16(w1t + 16384 + q * 512 + lane * 8, Bb1 + q * 512);
  }
  // strip: padded rows y2..y2+3, cols x0..x0+135, 68 chunks of 8 px, pure async
  for (int c = wid; c < 68; c += 8) {
    int ry = c / 17, ck = c - ry * 17;
    const ushort_t* g = xt + (((size_t)b * XTW + (y2 + ry)) * XTW + x0 + ck * 8) * 64 + lane * 8;
    gload_lds16(g, strip + (ry * 136 + ck * 8) * 64);
  }
  asm volatile("s_waitcnt vmcnt(0) lgkmcnt(0)" ::: "memory");
  asm volatile("s_barrier" ::: "memory");

  f32x4 acc[4][8] = {};

#pragma unroll
  for (int tap = 0; tap < 9; ++tap) {
    const int dy = tap / 3 - 1, dx = tap % 3 - 1;
    ushort_t* Bcur = (tap & 1) ? Bb1 : Bb0;
    if (tap < 8) {                     // prefetch next tap's weights into the other buf
      ushort_t* Bnxt = (tap & 1) ? Bb0 : Bb1;
      const ushort_t* gb = w1t + (tap + 1) * 16384;
#pragma unroll
      for (int j = 0; j < 4; ++j) {
        int q = (wid << 2) + j;
        gload_lds16(gb + q * 512 + lane * 8, Bnxt + q * 512);
      }
    }
    const int sr  = (wm >> 7) + dy + 1;      // strip row (wave-uniform)
    const int spb = (wm & 127) + dx + 1;     // strip px base
#pragma unroll
    for (int kk = 0; kk < 2; ++kk) {
      int c0 = (kk << 5) + (lg << 3);
      bf16x8 a[4];
#pragma unroll
      for (int m = 0; m < 4; ++m) {
        int sp = spb + m * 16 + l15;
        a[m] = *(const bf16x8*)(strip + ((sr * 136 + sp) << 6) + (c0 ^ ((sp & 7) << 3)));
      }
#pragma unroll
      for (int nf = 0; nf < 8; ++nf) {
        int br = wn + nf * 16 + l15;
        bf16x8 bb = *(const bf16x8*)(Bcur + (br << 6) + (c0 ^ ((br & 7) << 3)));
#pragma unroll
        for (int m = 0; m < 4; ++m)
          acc[m][nf] = MFMA(a[m], bb, acc[m][nf]);
      }
    }
    if (tap < 8) {                     // pf(tap+1) is the only thing outstanding
      asm volatile("s_waitcnt vmcnt(0)" ::: "memory");
      asm volatile("s_barrier" ::: "memory");
    }
  }
  __syncthreads();

  // conv1 epilogue: relu(acc + b1) -> F1 px-major, XOR-swizzled on ch by (p&7)
#pragma unroll
  for (int nf = 0; nf < 8; ++nf) {
    int ch = wn + nf * 16 + l15;
    float bias = b1[ch];
#pragma unroll
    for (int m = 0; m < 4; ++m) {
#pragma unroll
      for (int r = 0; r < 4; ++r) {
        int p = wm + m * 16 + lg * 4 + r;
        F1[(p << 8) + (ch ^ ((p & 7) << 3))] = f2b(fmaxf(acc[m][nf][r] + bias, 0.f));
      }
    }
  }
  // stage w2 (64 oc x 256 ic) -> W2l swizzled on ic by (oc&7)
#pragma unroll
  for (int it = 0; it < 4; ++it) {
    int u = it * 512 + tid;            // 2048 octets
    int oc = u >> 5, ic = (u & 31) << 3;
    float4 fa = *(const float4*)(w2 + (oc << 8) + ic);
    float4 fb = *(const float4*)(w2 + (oc << 8) + ic + 4);
    union { ushort_t s[8]; uint4 v; } pk;
    pk.s[0] = f2b(fa.x); pk.s[1] = f2b(fa.y); pk.s[2] = f2b(fa.z); pk.s[3] = f2b(fa.w);
    pk.s[4] = f2b(fb.x); pk.s[5] = f2b(fb.y); pk.s[6] = f2b(fb.z); pk.s[7] = f2b(fb.w);
    *(uint4*)(W2l + (oc << 8) + (ic ^ ((oc & 7) << 3))) = pk.v;
  }
  __syncthreads();
  // conv2: O[256 px][64 oc] = F1 @ W2^T; wave owns 32 px
  int wpx = wid << 5;
  f32x4 acc2[2][4] = {};
#pragma unroll
  for (int kc = 0; kc < 8; ++kc) {
    int c0 = (kc << 5) + (lg << 3);
    bf16x8 a2[2];
#pragma unroll
    for (int mm = 0; mm < 2; ++mm) {
      int p = wpx + mm * 16 + l15;
      a2[mm] = *(const bf16x8*)(F1 + (p << 8) + (c0 ^ ((p & 7) << 3)));
    }
#pragma unroll
    for (int nf = 0; nf < 4; ++nf) {
      int oc = nf * 16 + l15;
      bf16x8 bw = *(const bf16x8*)(W2l + (oc << 8) + (c0 ^ ((oc & 7) << 3)));
#pragma unroll
      for (int mm = 0; mm < 2; ++mm)
        acc2[mm][nf] = MFMA(a2[mm], bw, acc2[mm][nf]);
    }
  }
  __syncthreads();                     // all F1 reads done; T may overwrite
#pragma unroll
  for (int mm = 0; mm < 2; ++mm)
#pragma unroll
    for (int nf = 0; nf < 4; ++nf) {
      int oc = nf * 16 + l15;
      float bias = b2[oc];
#pragma unroll
      for (int r = 0; r < 4; ++r) {
        int p = wpx + mm * 16 + lg * 4 + r;
        T[(p << 6) + (oc ^ ((p & 7) << 3))] = f2b(acc2[mm][nf][r] + bias);
      }
    }
  __syncthreads();
  const size_t imgbase = (size_t)b * 65536;
#pragma unroll
  for (int it = 0; it < 4; ++it) {
    int u = it * 512 + tid;            // 2048 octets
    int p = u >> 3, co = (u & 7) << 3;
    uint4 v = *(const uint4*)(T + (p << 6) + (co ^ ((p & 7) << 3)));
    int gpx = (y2 + (p >> 7)) * 256 + x0 + (p & 127);
    *(uint4*)(f2 + (imgbase + gpx) * 64 + co) = v;
  }
}

// ---------------- bilinear sample -> fp[n][col ^ swz(n)] bf16 (PRE-SWIZZLED) ------
__global__ void sample_kernel(const ushort_t* __restrict__ f2, const float* __restrict__ pts,
                              const int* __restrict__ ct_b, ushort_t* __restrict__ fp) {
  int n = blockIdx.x, t = threadIdx.x;   // 2000 x 128
  __shared__ float pl[258];
  __shared__ __align__(16) ushort_t fpl[8256];   // [64][129]
  int b = ct_b[n];
  const ushort_t* fb = f2 + (size_t)b * 4194304;
  for (int i = t; i < 258; i += 128) pl[i] = pts[(size_t)n * 258 + i];
  __syncthreads();
  int c4 = t & 15;            // channel quad: ch = 4*c4 .. 4*c4+3
  int ps = t >> 4;            // 0..7 point slot
  for (int base = 0; base < 136; base += 8) {
    int pt = base + ps;
    bool live = pt < 129;
    int ptc = live ? pt : 0;
    float px = pl[ptc * 2], py = pl[ptc * 2 + 1];
    float sx = px - 0.5f, sy = py - 0.5f;
    float fx0 = floorf(sx), fy0 = floorf(sy);
    int x0 = (int)fx0, y0 = (int)fy0;
    float wx1 = sx - fx0, wy1 = sy - fy0;
    float wx0 = 1.f - wx1, wy0 = 1.f - wy1;
    float a0 = 0.f, a1 = 0.f, a2 = 0.f, a3 = 0.f;
#pragma unroll
    for (int cy = 0; cy < 2; ++cy) {
#pragma unroll
      for (int cx = 0; cx < 2; ++cx) {
        int yc = y0 + cy, xc = x0 + cx;
        float w = (cy ? wy1 : wy0) * (cx ? wx1 : wx0);
        bool valid = (xc >= 0) && (xc < 256) && (yc >= 0) && (yc < 256);
        int ycc = min(max(yc, 0), 255), xcc = min(max(xc, 0), 255);
        uint2 v = *(const uint2*)(fb + ((size_t)(ycc * 256 + xcc)) * 64 + (c4 << 2));
        float ww = valid ? w : 0.f;
        a0 += b2f((ushort_t)(v.x & 0xFFFF)) * ww;
        a1 += b2f((ushort_t)(v.x >> 16)) * ww;
        a2 += b2f((ushort_t)(v.y & 0xFFFF)) * ww;
        a3 += b2f((ushort_t)(v.y >> 16)) * ww;
      }
    }
    if (live) {
      int ch = c4 << 2;
      fpl[(ch + 0) * 129 + pt] = f2b(a0);
      fpl[(ch + 1) * 129 + pt] = f2b(a1);
      fpl[(ch + 2) * 129 + pt] = f2b(a2);
      fpl[(ch + 3) * 129 + pt] = f2b(a3);
    }
  }
  __syncthreads();
  uint4* fo = (uint4*)(fp + (size_t)n * 8256);
  const uint4* fi = (const uint4*)fpl;
  int key = n & 7;
  for (int i = t; i < 1032; i += 128) fo[i ^ key] = fi[i];
}

// ---------------- split-K GEMM1: 128x128 tiles, partials[kc][2048][512] f32 -------
// A = fp (pre-swizzled), B = wpb (pre-swizzled). grid (64 spatial, 8 kc).
// XCD map: n_t = (spatial&7)>>1 so each XCD reuses ONE 2 MB B-panel in its L2.
__global__ __launch_bounds__(256)
void gemm_splitk_kernel(const ushort_t* __restrict__ A, const ushort_t* __restrict__ B,
                        float* __restrict__ partials) {
  __shared__ __align__(16) ushort_t Al[8192];   // [128][64] swizzled
  __shared__ __align__(16) ushort_t Bl[8192];
  int spatial = blockIdx.x;                      // 64
  int kc = blockIdx.y;                           // 8
  int n_t = (spatial & 7) >> 1;                  // 0..3 (XCD-locked)
  int m_t = ((spatial >> 3) << 1) | (spatial & 1);   // 0..15
  int m0 = m_t << 7, n0 = n_t << 7;
  int ks0 = (129 * kc) >> 3, ks1 = (129 * (kc + 1)) >> 3;   // 64-wide k-steps

  int tid = threadIdx.x;
  int wid = tid >> 6, lane = tid & 63;
  int l15 = lane & 15, lg = lane >> 4;
  int wm = (wid >> 1) << 6, wn = (wid & 1) << 6;
  int srow = (lane >> 3);                        // stage row-in-octet
  int soct = lane & 7;
  f32x4 acc[4][4] = {};
  for (int ks = ks0; ks < ks1; ++ks) {
    __syncthreads();
#pragma unroll
    for (int j = 0; j < 4; ++j) {
      int q = (wid << 2) + j;                    // 16 chunks of 1024 B
      int r = (q << 3) + srow;                   // tile row 0..127
      int ar = m0 + r;
      if (ar >= 2000) ar = 1992 + (ar & 7);      // clamp, swizzle-key preserved
      gload_lds16(A + (size_t)ar * 8256 + ks * 64 + soct * 8, Al + q * 512);
      gload_lds16(B + (size_t)(n0 + r) * 8256 + ks * 64 + soct * 8, Bl + q * 512);
    }
    __syncthreads();
#pragma unroll
    for (int kk = 0; kk < 2; ++kk) {
      int c0 = (kk << 5) + (lg << 3);
      bf16x8 a[4], b[4];
#pragma unroll
      for (int m = 0; m < 4; ++m) {
        int row = wm + m * 16 + l15;
        a[m] = *(const bf16x8*)(Al + (row << 6) + (c0 ^ ((row & 7) << 3)));
      }
#pragma unroll
      for (int nf = 0; nf < 4; ++nf) {
        int row = wn + nf * 16 + l15;
        b[nf] = *(const bf16x8*)(Bl + (row << 6) + (c0 ^ ((row & 7) << 3)));
      }
#pragma unroll
      for (int m = 0; m < 4; ++m)
#pragma unroll
        for (int nf = 0; nf < 4; ++nf)
          acc[m][nf] = MFMA(a[m], b[nf], acc[m][nf]);
    }
  }
  float* pout = partials + (size_t)kc * 1048576;   // 2048*512
#pragma unroll
  for (int m = 0; m < 4; ++m)
#pragma unroll
    for (int nf = 0; nf < 4; ++nf)
#pragma unroll
      for (int r = 0; r < 4; ++r) {
        int row = m0 + wm + m * 16 + lg * 4 + r;
        int col = n0 + wn + nf * 16 + l15;
        pout[(size_t)row * 512 + col] = acc[m][nf][r];
      }
}

// ---------------- reduce 8 partials -> off1 bf16 [2048][512] ----------------
__global__ void reduce_splitk_kernel(const float* __restrict__ partials,
                                     ushort_t* __restrict__ off1) {
  int i = blockIdx.x * 256 + threadIdx.x;    // 262144 threads x 4 elems
  size_t idx = (size_t)i * 4;
  float4 s = *(const float4*)(partials + idx);
#pragma unroll
  for (int c = 1; c < 8; ++c) {
    float4 p = *(const float4*)(partials + (size_t)c * 1048576 + idx);
    s.x += p.x; s.y += p.y; s.z += p.z; s.w += p.w;
  }
  union { ushort_t u[4]; uint2 v; } pk;
  pk.u[0] = f2b(s.x); pk.u[1] = f2b(s.y); pk.u[2] = f2b(s.z); pk.u[3] = f2b(s.w);
  *(uint2*)(off1 + idx) = pk.v;
}

// ---------------- GEMM2: off1 @ wfb^T + bias -> out (64x64 tiles) ----------------
__global__ __launch_bounds__(256)
void gemm64_epi_kernel(const ushort_t* __restrict__ A, const ushort_t* __restrict__ B,
                       const float* __restrict__ bias, const float* __restrict__ out0,
                       float* __restrict__ out1, int Mvalid) {
  __shared__ ushort_t Alds[64][72];
  __shared__ ushort_t Blds[64][72];
  const int K = 512;
  int n0 = blockIdx.x * 64, m0 = blockIdx.y * 64;
  int tid = threadIdx.x;
  int wid = tid >> 6, lane = tid & 63;
  int l15 = lane & 15, lg = lane >> 4;
  int wm = (wid >> 1) * 32, wn = (wid & 1) * 32;
  f32x4 acc[2][2] = {};
  for (int ks = 0; ks < K / 64; ++ks) {
    __syncthreads();
#pragma unroll
    for (int it = 0; it < 2; ++it) {
      int u = it * 256 + tid;
      int r = u >> 3, cc = (u & 7) << 3;
      *(uint4*)(&Alds[r][cc]) = *(const uint4*)(A + (size_t)(m0 + r) * K + ks * 64 + cc);
      *(uint4*)(&Blds[r][cc]) = *(const uint4*)(B + (size_t)(n0 + r) * K + ks * 64 + cc);
    }
    __syncthreads();
#pragma unroll
    for (int kk = 0; kk < 2; ++kk) {
      int c0 = (kk << 5) + (lg << 3);
      bf16x8 a[2], b[2];
      a[0] = *(const bf16x8*)(&Alds[wm + l15][c0]);
      a[1] = *(const bf16x8*)(&Alds[wm + 16 + l15][c0]);
      b[0] = *(const bf16x8*)(&Blds[wn + l15][c0]);
      b[1] = *(const bf16x8*)(&Blds[wn + 16 + l15][c0]);
#pragma unroll
      for (int m = 0; m < 2; ++m)
#pragma unroll
        for (int nf = 0; nf < 2; ++nf)
          acc[m][nf] = MFMA(a[m], b[nf], acc[m][nf]);
    }
  }
#pragma unroll
  for (int m = 0; m < 2; ++m)
#pragma unroll
    for (int nf = 0; nf < 2; ++nf)
#pragma unroll
      for (int r = 0; r < 4; ++r) {
        int row = m0 + wm + m * 16 + lg * 4 + r;
        int col = n0 + wn + nf * 16 + l15;
        if (row < Mvalid) {
          float v = acc[m][nf][r] + bias[col];
          out1[(size_t)row * 256 + col] = v * 16.f + out0[(size_t)row * 256 + col];
        }
      }
}

// ---------------- launch ----------------
extern "C" void kernel_launch(void* const* d_in, const int* in_sizes, int n_in,
                              void* d_out, int out_size, void* d_ws, size_t ws_size,
                              hipStream_t stream) {
  const float* x    = (const float*)d_in[0];
  const float* wh   = (const float*)d_in[1];
  const int* ct_ind = (const int*)d_in[2];
  const int* ct_b   = (const int*)d_in[3];
  const float* w1   = (const float*)d_in[4];
  const float* b1   = (const float*)d_in[5];
  const float* w2   = (const float*)d_in[6];
  const float* b2   = (const float*)d_in[7];
  const float* wp   = (const float*)d_in[8];
  const float* wf   = (const float*)d_in[9];
  const float* bfu  = (const float*)d_in[10];
  float* out = (float*)d_out;
  char* ws = (char*)d_ws;

  // ws map (bytes):
  ushort_t* xt    = (ushort_t*)(ws + 0);            // 34,080,768 (4*258*258*64*2)
  float* partials = (float*)(ws + 0);               // 33,554,432 (aliases xt, dead after conv)
  ushort_t* w1t   = (ushort_t*)(ws + 34080768);     //    294,912
  ushort_t* f2    = (ushort_t*)(ws + 34375680);     // 33,554,432
  ushort_t* wpb   = (ushort_t*)(ws + 67930112);     //  8,454,144
  ushort_t* wfb   = (ushort_t*)(ws + 76384256);     //    262,144
  ushort_t* fp    = (ushort_t*)(ws + 76646400);     // 33,024,000 (2000 rows, swizzled)
  ushort_t* off1  = (ushort_t*)(ws + 109670400);    //  2,097,152 (2048x512)
  float*    pts   = (float*)(ws + 111767552);       //  2,064,000  (end 113,831,552)

  zero_border_kernel<<<dim3(129), dim3(256), 0, stream>>>(xt);
  cast_xt_kernel<<<dim3(4096), dim3(256), 0, stream>>>(x, xt);
  cast_w1t_kernel<<<dim3(576), dim3(256), 0, stream>>>(w1, w1t);
  cast_wp_kernel<<<dim3(2064), dim3(256), 0, stream>>>(wp, wpb);
  cast_f32_bf16_kernel<<<dim3(64), dim3(256), 0, stream>>>(wf, wfb, 131072);
  prep_kernel<<<dim3(2000), dim3(128), 0, stream>>>(wh, ct_ind, ct_b, out, pts);
  conv_fused_kernel<<<dim3(1024), dim3(512), 0, stream>>>(xt, w1t, b1, w2, b2, f2);
  sample_kernel<<<dim3(2000), dim3(128), 0, stream>>>(f2, pts, ct_b, fp);
  gemm_splitk_kernel<<<dim3(64, 8), dim3(256), 0, stream>>>(fp, wpb, partials);
  reduce_splitk_kernel<<<dim3(1024), dim3(256), 0, stream>>>(partials, off1);
  gemm64_epi_kernel<<<dim3(4, 32), dim3(256), 0, stream>>>(off1, wfb, bfu, out,
                                                           out + 512000, 2000);
}

// Round 11
// 200.100 us; speedup vs baseline: 1.5417x; 1.1064x over previous
//
#include <hip/hip_runtime.h>

typedef unsigned short ushort_t;
typedef __bf16 bf16x8 __attribute__((ext_vector_type(8)));
typedef float f32x4 __attribute__((ext_vector_type(4)));

__device__ __forceinline__ ushort_t f2b(float f) {
  union { float f; unsigned u; } v; v.f = f;
  unsigned r = v.u + 0x7FFFu + ((v.u >> 16) & 1u);
  return (ushort_t)(r >> 16);
}
__device__ __forceinline__ float b2f(ushort_t u) {
  union { unsigned u; float f; } v; v.u = ((unsigned)u) << 16;
  return v.f;
}
__device__ __forceinline__ f32x4 MFMA(bf16x8 a, bf16x8 b, f32x4 c) {
  return __builtin_amdgcn_mfma_f32_16x16x32_bf16(a, b, c, 0, 0, 0);
}
// async global->LDS, 16 B per lane; lds base must be wave-uniform
__device__ __forceinline__ void gload_lds16(const ushort_t* g, ushort_t* l) {
  __builtin_amdgcn_global_load_lds(
      (const __attribute__((address_space(1))) unsigned int*)g,
      (__attribute__((address_space(3))) unsigned int*)l, 16, 0, 0);
}

// xt_pad geometry: [4][258 rows][258 cols][64 ch] bf16, 1-px zero border,
// channel octet stored at slot c ^ ((col&7)<<3)  (pre-swizzled for LDS)
#define XTW 258

// -------- cast cnn_feature NCHW f32 -> padded+swizzled NHWC bf16 (+ border) ------
// grid 4225: blocks <4096 cast; blocks >=4096 zero the border rows/cols.
__global__ void cast_xt_kernel(const float* __restrict__ x, ushort_t* __restrict__ xt) {
  __shared__ float tile[64][65];
  int blk = blockIdx.x;
  int t = threadIdx.x;                // 256
  if (blk >= 4096) {                  // border: 32896 uint4 writes
    int i = (blk - 4096) * 256 + t;
    if (i < 32896) {
      int px_id = i >> 3, oct = (i & 7) << 3;
      int img = px_id / 1028, r = px_id - img * 1028;
      int row, col;
      if (r < 516) { row = (r < 258) ? 0 : 257; col = (r < 258) ? r : r - 258; }
      else { int rr = r - 516; row = 1 + (rr >> 1); col = (rr & 1) ? 257 : 0; }
      uint4 z = make_uint4(0, 0, 0, 0);
      *(uint4*)(xt + (((size_t)img * XTW + row) * XTW + col) * 64 + oct) = z;
    }
    return;
  }
  int b = blk >> 10, rest = blk & 1023;
  int y = rest >> 2, xseg = (rest & 3) << 6;
  int p0 = y * 256 + xseg;
#pragma unroll
  for (int rep = 0; rep < 16; ++rep) {
    int lin = rep * 256 + t;
    int c = lin >> 6, p = lin & 63;
    tile[c][p] = x[((size_t)(b * 64 + c)) * 65536 + p0 + p];
  }
  __syncthreads();
#pragma unroll
  for (int rep = 0; rep < 2; ++rep) {
    int u = rep * 256 + t;            // 512 units of 8ch
    int p = u >> 3, cc = (u & 7) << 3;
    union { ushort_t s[8]; uint4 v; } pk;
#pragma unroll
    for (int j = 0; j < 8; ++j) pk.s[j] = f2b(tile[cc + j][p]);
    int gx = xseg + p + 1;
    size_t base = (((size_t)b * XTW + (y + 1)) * XTW + gx) * 64;
    *(uint4*)(xt + base + (cc ^ ((gx & 7) << 3))) = pk.v;
  }
}

// -------- setup: w1t cast + wpb cast(swz) + wfb cast + prep, fused by blk range ---
// [0,576): w1t  [576,2640): wpb  [2640,2704): wfb  [2704,3704): prep (2 inst/blk)
__global__ void setup_kernel(const float* __restrict__ w1, ushort_t* __restrict__ w1t,
                             const float* __restrict__ wp, ushort_t* __restrict__ wpb,
                             const float* __restrict__ wf, ushort_t* __restrict__ wfb,
                             const float* __restrict__ wh, const int* __restrict__ ct_ind,
                             const int* __restrict__ ct_b, float* __restrict__ out,
                             float* __restrict__ pts) {
  int blk = blockIdx.x, t = threadIdx.x;
  if (blk < 576) {
    int i = blk * 256 + t;            // 147456 total
    int tap = i >> 14;
    int rem = i & 16383;
    int nn = rem >> 6, c = rem & 63;
    int cs = c ^ ((nn & 7) << 3);
    w1t[tap * 16384 + nn * 64 + cs] = f2b(w1[(nn * 64 + c) * 9 + tap]);
  } else if (blk < 2640) {
    for (int i = (blk - 576) * 256 + t; i < 4227072; i += 2064 * 256) {
      int row = i / 8256;
      int col = i - row * 8256;
      wpb[row * 8256 + (col ^ ((row & 7) << 3))] = f2b(wp[i]);
    }
  } else if (blk < 2704) {
    for (int i = (blk - 2640) * 256 + t; i < 131072; i += 64 * 256)
      wfb[i] = f2b(wf[i]);
  } else {
    int n = (blk - 2704) * 2 + (t >> 7);
    int t7 = t & 127;
    int ci = ct_ind[n];
    int b = ct_b[n];
    int ctx = ci & 255;
    int cty = (ci >> 8) & 255;
    float fx = (float)ctx, fy = (float)cty;
    size_t base = ((size_t)b * 256 + 2 * t7) * 65536 + (size_t)cty * 256 + ctx;
    float ox = wh[base];
    float oy = wh[base + 65536];
    float ix = ox * 10.f + fx, iy = oy * 10.f + fy;
    out[(n * 128 + t7) * 2]     = ix * 4.f;
    out[(n * 128 + t7) * 2 + 1] = iy * 4.f;
    float* pn = pts + (size_t)n * 258;
    if (t7 == 0) { pn[0] = fx; pn[1] = fy; }
    pn[2 + t7 * 2] = ix;
    pn[3 + t7 * 2] = iy;
  }
}

// ---------------- fused conv1(3x3)+bias+relu + conv2(1x1)+bias -> f2 NHWC bf16 ----
// 2-row blocks: M=256 px (2 rows x 128), N=256 ch, 8 waves, wave-tile 64x128.
// 4-row strip staged once via async gload_lds; 2-deep LDS weight buffers.
// (Best-measured conv variant; byte-identical to R10.)
__global__ __launch_bounds__(512, 1)
void conv_fused_kernel(const ushort_t* __restrict__ xt, const ushort_t* __restrict__ w1t,
                       const float* __restrict__ b1, const float* __restrict__ w2,
                       const float* __restrict__ b2, ushort_t* __restrict__ f2) {
  __shared__ __align__(16) char smem[163840];
  ushort_t* strip = (ushort_t*)smem;              // [4][136][64] = 69632 B
  ushort_t* Bb0   = (ushort_t*)(smem + 69632);    // [256][64] = 32768 B
  ushort_t* Bb1   = (ushort_t*)(smem + 102400);   // ends 135168
  ushort_t* F1    = (ushort_t*)smem;              // [256][256] = 131072 (epilogue)
  ushort_t* W2l   = (ushort_t*)(smem + 131072);   // [64][256] = 32768 (epilogue)
  ushort_t* T     = (ushort_t*)smem;              // [256][64] (store stage)

  int rawblk = blockIdx.x;                         // 1024
  int blk = ((rawblk & 7) << 7) + (rawblk >> 3);   // bijective XCD swizzle (1024%8==0)
  int b = blk >> 8;
  int rest = blk & 255;
  int y2 = (rest >> 1) << 1;                       // first output row (even)
  int x0 = (rest & 1) << 7;                        // 0 or 128
  int tid = threadIdx.x;
  int wid = tid >> 6, lane = tid & 63;
  int l15 = lane & 15, lg = lane >> 4;
  int wm = (wid >> 1) << 6;    // px offset: 0,64,128,192
  int wn = (wid & 1) << 7;     // ch offset: 0,128

  // prologue: issue weight pf for taps 0,1 (linear dest = pre-swizzled layout)
#pragma unroll
  for (int j = 0; j < 4; ++j) {
    int q = (wid << 2) + j;            // 32 chunks of 1024 B
    gload_lds16(w1t + q * 512 + lane * 8, Bb0 + q * 512);
  }
#pragma unroll
  for (int j = 0; j < 4; ++j) {
    int q = (wid << 2) + j;
    gload_lds16(w1t + 16384 + q * 512 + lane * 8, Bb1 + q * 512);
  }
  // strip: padded rows y2..y2+3, cols x0..x0+135, 68 chunks of 8 px, pure async
  for (int c = wid; c < 68; c += 8) {
    int ry = c / 17, ck = c - ry * 17;
    const ushort_t* g = xt + (((size_t)b * XTW + (y2 + ry)) * XTW + x0 + ck * 8) * 64 + lane * 8;
    gload_lds16(g, strip + (ry * 136 + ck * 8) * 64);
  }
  asm volatile("s_waitcnt vmcnt(0) lgkmcnt(0)" ::: "memory");
  asm volatile("s_barrier" ::: "memory");

  f32x4 acc[4][8] = {};

#pragma unroll
  for (int tap = 0; tap < 9; ++tap) {
    const int dy = tap / 3 - 1, dx = tap % 3 - 1;
    ushort_t* Bcur = (tap & 1) ? Bb1 : Bb0;
    if (tap < 8) {                     // prefetch next tap's weights into the other buf
      ushort_t* Bnxt = (tap & 1) ? Bb0 : Bb1;
      const ushort_t* gb = w1t + (tap + 1) * 16384;
#pragma unroll
      for (int j = 0; j < 4; ++j) {
        int q = (wid << 2) + j;
        gload_lds16(gb + q * 512 + lane * 8, Bnxt + q * 512);
      }
    }
    const int sr  = (wm >> 7) + dy + 1;      // strip row (wave-uniform)
    const int spb = (wm & 127) + dx + 1;     // strip px base
#pragma unroll
    for (int kk = 0; kk < 2; ++kk) {
      int c0 = (kk << 5) + (lg << 3);
      bf16x8 a[4];
#pragma unroll
      for (int m = 0; m < 4; ++m) {
        int sp = spb + m * 16 + l15;
        a[m] = *(const bf16x8*)(strip + ((sr * 136 + sp) << 6) + (c0 ^ ((sp & 7) << 3)));
      }
#pragma unroll
      for (int nf = 0; nf < 8; ++nf) {
        int br = wn + nf * 16 + l15;
        bf16x8 bb = *(const bf16x8*)(Bcur + (br << 6) + (c0 ^ ((br & 7) << 3)));
#pragma unroll
        for (int m = 0; m < 4; ++m)
          acc[m][nf] = MFMA(a[m], bb, acc[m][nf]);
      }
    }
    if (tap < 8) {                     // pf(tap+1) is the only thing outstanding
      asm volatile("s_waitcnt vmcnt(0)" ::: "memory");
      asm volatile("s_barrier" ::: "memory");
    }
  }
  __syncthreads();

  // conv1 epilogue: relu(acc + b1) -> F1 px-major, XOR-swizzled on ch by (p&7)
#pragma unroll
  for (int nf = 0; nf < 8; ++nf) {
    int ch = wn + nf * 16 + l15;
    float bias = b1[ch];
#pragma unroll
    for (int m = 0; m < 4; ++m) {
#pragma unroll
      for (int r = 0; r < 4; ++r) {
        int p = wm + m * 16 + lg * 4 + r;
        F1[(p << 8) + (ch ^ ((p & 7) << 3))] = f2b(fmaxf(acc[m][nf][r] + bias, 0.f));
      }
    }
  }
  // stage w2 (64 oc x 256 ic) -> W2l swizzled on ic by (oc&7)
#pragma unroll
  for (int it = 0; it < 4; ++it) {
    int u = it * 512 + tid;            // 2048 octets
    int oc = u >> 5, ic = (u & 31) << 3;
    float4 fa = *(const float4*)(w2 + (oc << 8) + ic);
    float4 fb = *(const float4*)(w2 + (oc << 8) + ic + 4);
    union { ushort_t s[8]; uint4 v; } pk;
    pk.s[0] = f2b(fa.x); pk.s[1] = f2b(fa.y); pk.s[2] = f2b(fa.z); pk.s[3] = f2b(fa.w);
    pk.s[4] = f2b(fb.x); pk.s[5] = f2b(fb.y); pk.s[6] = f2b(fb.z); pk.s[7] = f2b(fb.w);
    *(uint4*)(W2l + (oc << 8) + (ic ^ ((oc & 7) << 3))) = pk.v;
  }
  __syncthreads();
  // conv2: O[256 px][64 oc] = F1 @ W2^T; wave owns 32 px
  int wpx = wid << 5;
  f32x4 acc2[2][4] = {};
#pragma unroll
  for (int kc = 0; kc < 8; ++kc) {
    int c0 = (kc << 5) + (lg << 3);
    bf16x8 a2[2];
#pragma unroll
    for (int mm = 0; mm < 2; ++mm) {
      int p = wpx + mm * 16 + l15;
      a2[mm] = *(const bf16x8*)(F1 + (p << 8) + (c0 ^ ((p & 7) << 3)));
    }
#pragma unroll
    for (int nf = 0; nf < 4; ++nf) {
      int oc = nf * 16 + l15;
      bf16x8 bw = *(const bf16x8*)(W2l + (oc << 8) + (c0 ^ ((oc & 7) << 3)));
#pragma unroll
      for (int mm = 0; mm < 2; ++mm)
        acc2[mm][nf] = MFMA(a2[mm], bw, acc2[mm][nf]);
    }
  }
  __syncthreads();                     // all F1 reads done; T may overwrite
#pragma unroll
  for (int mm = 0; mm < 2; ++mm)
#pragma unroll
    for (int nf = 0; nf < 4; ++nf) {
      int oc = nf * 16 + l15;
      float bias = b2[oc];
#pragma unroll
      for (int r = 0; r < 4; ++r) {
        int p = wpx + mm * 16 + lg * 4 + r;
        T[(p << 6) + (oc ^ ((p & 7) << 3))] = f2b(acc2[mm][nf][r] + bias);
      }
    }
  __syncthreads();
  const size_t imgbase = (size_t)b * 65536;
#pragma unroll
  for (int it = 0; it < 4; ++it) {
    int u = it * 512 + tid;            // 2048 octets
    int p = u >> 3, co = (u & 7) << 3;
    uint4 v = *(const uint4*)(T + (p << 6) + (co ^ ((p & 7) << 3)));
    int gpx = (y2 + (p >> 7)) * 256 + x0 + (p & 127);
    *(uint4*)(f2 + (imgbase + gpx) * 64 + co) = v;
  }
}

// ---------------- bilinear sample -> fp[n][col ^ swz(n)] bf16 (PRE-SWIZZLED) ------
__global__ void sample_kernel(const ushort_t* __restrict__ f2, const float* __restrict__ pts,
                              const int* __restrict__ ct_b, ushort_t* __restrict__ fp) {
  int n = blockIdx.x, t = threadIdx.x;   // 2000 x 128
  __shared__ float pl[258];
  __shared__ __align__(16) ushort_t fpl[8256];   // [64][129]
  int b = ct_b[n];
  const ushort_t* fb = f2 + (size_t)b * 4194304;
  for (int i = t; i < 258; i += 128) pl[i] = pts[(size_t)n * 258 + i];
  __syncthreads();
  int c4 = t & 15;            // channel quad: ch = 4*c4 .. 4*c4+3
  int ps = t >> 4;            // 0..7 point slot
  for (int base = 0; base < 136; base += 8) {
    int pt = base + ps;
    bool live = pt < 129;
    int ptc = live ? pt : 0;
    float px = pl[ptc * 2], py = pl[ptc * 2 + 1];
    float sx = px - 0.5f, sy = py - 0.5f;
    float fx0 = floorf(sx), fy0 = floorf(sy);
    int x0 = (int)fx0, y0 = (int)fy0;
    float wx1 = sx - fx0, wy1 = sy - fy0;
    float wx0 = 1.f - wx1, wy0 = 1.f - wy1;
    float a0 = 0.f, a1 = 0.f, a2 = 0.f, a3 = 0.f;
#pragma unroll
    for (int cy = 0; cy < 2; ++cy) {
#pragma unroll
      for (int cx = 0; cx < 2; ++cx) {
        int yc = y0 + cy, xc = x0 + cx;
        float w = (cy ? wy1 : wy0) * (cx ? wx1 : wx0);
        bool valid = (xc >= 0) && (xc < 256) && (yc >= 0) && (yc < 256);
        int ycc = min(max(yc, 0), 255), xcc = min(max(xc, 0), 255);
        uint2 v = *(const uint2*)(fb + ((size_t)(ycc * 256 + xcc)) * 64 + (c4 << 2));
        float ww = valid ? w : 0.f;
        a0 += b2f((ushort_t)(v.x & 0xFFFF)) * ww;
        a1 += b2f((ushort_t)(v.x >> 16)) * ww;
        a2 += b2f((ushort_t)(v.y & 0xFFFF)) * ww;
        a3 += b2f((ushort_t)(v.y >> 16)) * ww;
      }
    }
    if (live) {
      int ch = c4 << 2;
      fpl[(ch + 0) * 129 + pt] = f2b(a0);
      fpl[(ch + 1) * 129 + pt] = f2b(a1);
      fpl[(ch + 2) * 129 + pt] = f2b(a2);
      fpl[(ch + 3) * 129 + pt] = f2b(a3);
    }
  }
  __syncthreads();
  uint4* fo = (uint4*)(fp + (size_t)n * 8256);
  const uint4* fi = (const uint4*)fpl;
  int key = n & 7;
  for (int i = t; i < 1032; i += 128) fo[i ^ key] = fi[i];
}

// ---------------- split-K GEMM1: 128x128 tiles, partials[kc][2048][512] BF16 ------
// A = fp (pre-swizzled), B = wpb (pre-swizzled). grid (64 spatial, 8 kc).
// XCD map: n_t = (spatial&7)>>1 so each XCD reuses ONE 2 MB B-panel in its L2.
__global__ __launch_bounds__(256)
void gemm_splitk_kernel(const ushort_t* __restrict__ A, const ushort_t* __restrict__ B,
                        ushort_t* __restrict__ partials) {
  __shared__ __align__(16) ushort_t Al[8192];   // [128][64] swizzled
  __shared__ __align__(16) ushort_t Bl[8192];
  int spatial = blockIdx.x;                      // 64
  int kc = blockIdx.y;                           // 8
  int n_t = (spatial & 7) >> 1;                  // 0..3 (XCD-locked)
  int m_t = ((spatial >> 3) << 1) | (spatial & 1);   // 0..15
  int m0 = m_t << 7, n0 = n_t << 7;
  int ks0 = (129 * kc) >> 3, ks1 = (129 * (kc + 1)) >> 3;   // 64-wide k-steps

  int tid = threadIdx.x;
  int wid = tid >> 6, lane = tid & 63;
  int l15 = lane & 15, lg = lane >> 4;
  int wm = (wid >> 1) << 6, wn = (wid & 1) << 6;
  int srow = (lane >> 3);                        // stage row-in-octet
  int soct = lane & 7;
  f32x4 acc[4][4] = {};
  for (int ks = ks0; ks < ks1; ++ks) {
    __syncthreads();
#pragma unroll
    for (int j = 0; j < 4; ++j) {
      int q = (wid << 2) + j;                    // 16 chunks of 1024 B
      int r = (q << 3) + srow;                   // tile row 0..127
      int ar = m0 + r;
      if (ar >= 2000) ar = 1992 + (ar & 7);      // clamp, swizzle-key preserved
      gload_lds16(A + (size_t)ar * 8256 + ks * 64 + soct * 8, Al + q * 512);
      gload_lds16(B + (size_t)(n0 + r) * 8256 + ks * 64 + soct * 8, Bl + q * 512);
    }
    __syncthreads();
#pragma unroll
    for (int kk = 0; kk < 2; ++kk) {
      int c0 = (kk << 5) + (lg << 3);
      bf16x8 a[4], b[4];
#pragma unroll
      for (int m = 0; m < 4; ++m) {
        int row = wm + m * 16 + l15;
        a[m] = *(const bf16x8*)(Al + (row << 6) + (c0 ^ ((row & 7) << 3)));
      }
#pragma unroll
      for (int nf = 0; nf < 4; ++nf) {
        int row = wn + nf * 16 + l15;
        b[nf] = *(const bf16x8*)(Bl + (row << 6) + (c0 ^ ((row & 7) << 3)));
      }
#pragma unroll
      for (int m = 0; m < 4; ++m)
#pragma unroll
        for (int nf = 0; nf < 4; ++nf)
          acc[m][nf] = MFMA(a[m], b[nf], acc[m][nf]);
    }
  }
  ushort_t* pout = partials + (size_t)kc * 1048576;   // 2048*512 bf16
#pragma unroll
  for (int m = 0; m < 4; ++m)
#pragma unroll
    for (int nf = 0; nf < 4; ++nf)
#pragma unroll
      for (int r = 0; r < 4; ++r) {
        int row = m0 + wm + m * 16 + lg * 4 + r;
        int col = n0 + wn + nf * 16 + l15;
        pout[(size_t)row * 512 + col] = f2b(acc[m][nf][r]);
      }
}

// ---------------- reduce 8 bf16 partials -> off1 bf16 [2048][512] ----------------
__global__ void reduce_splitk_kernel(const ushort_t* __restrict__ partials,
                                     ushort_t* __restrict__ off1) {
  int i = blockIdx.x * 256 + threadIdx.x;    // 131072 threads x 8 elems
  size_t idx = (size_t)i * 8;
  float s[8] = {0.f, 0.f, 0.f, 0.f, 0.f, 0.f, 0.f, 0.f};
#pragma unroll
  for (int c = 0; c < 8; ++c) {
    uint4 v = *(const uint4*)(partials + (size_t)c * 1048576 + idx);
    s[0] += b2f((ushort_t)(v.x & 0xFFFF)); s[1] += b2f((ushort_t)(v.x >> 16));
    s[2] += b2f((ushort_t)(v.y & 0xFFFF)); s[3] += b2f((ushort_t)(v.y >> 16));
    s[4] += b2f((ushort_t)(v.z & 0xFFFF)); s[5] += b2f((ushort_t)(v.z >> 16));
    s[6] += b2f((ushort_t)(v.w & 0xFFFF)); s[7] += b2f((ushort_t)(v.w >> 16));
  }
  union { ushort_t u[8]; uint4 v; } pk;
#pragma unroll
  for (int j = 0; j < 8; ++j) pk.u[j] = f2b(s[j]);
  *(uint4*)(off1 + idx) = pk.v;
}

// ---------------- GEMM2: off1 @ wfb^T + bias -> out (64x64 tiles) ----------------
__global__ __launch_bounds__(256)
void gemm64_epi_kernel(const ushort_t* __restrict__ A, const ushort_t* __restrict__ B,
                       const float* __restrict__ bias, const float* __restrict__ out0,
                       float* __restrict__ out1, int Mvalid) {
  __shared__ ushort_t Alds[64][72];
  __shared__ ushort_t Blds[64][72];
  const int K = 512;
  int n0 = blockIdx.x * 64, m0 = blockIdx.y * 64;
  int tid = threadIdx.x;
  int wid = tid >> 6, lane = tid & 63;
  int l15 = lane & 15, lg = lane >> 4;
  int wm = (wid >> 1) * 32, wn = (wid & 1) * 32;
  f32x4 acc[2][2] = {};
  for (int ks = 0; ks < K / 64; ++ks) {
    __syncthreads();
#pragma unroll
    for (int it = 0; it < 2; ++it) {
      int u = it * 256 + tid;
      int r = u >> 3, cc = (u & 7) << 3;
      *(uint4*)(&Alds[r][cc]) = *(const uint4*)(A + (size_t)(m0 + r) * K + ks * 64 + cc);
      *(uint4*)(&Blds[r][cc]) = *(const uint4*)(B + (size_t)(n0 + r) * K + ks * 64 + cc);
    }
    __syncthreads();
#pragma unroll
    for (int kk = 0; kk < 2; ++kk) {
      int c0 = (kk << 5) + (lg << 3);
      bf16x8 a[2], b[2];
      a[0] = *(const bf16x8*)(&Alds[wm + l15][c0]);
      a[1] = *(const bf16x8*)(&Alds[wm + 16 + l15][c0]);
      b[0] = *(const bf16x8*)(&Blds[wn + l15][c0]);
      b[1] = *(const bf16x8*)(&Blds[wn + 16 + l15][c0]);
#pragma unroll
      for (int m = 0; m < 2; ++m)
#pragma unroll
        for (int nf = 0; nf < 2; ++nf)
          acc[m][nf] = MFMA(a[m], b[nf], acc[m][nf]);
    }
  }
#pragma unroll
  for (int m = 0; m < 2; ++m)
#pragma unroll
    for (int nf = 0; nf < 2; ++nf)
#pragma unroll
      for (int r = 0; r < 4; ++r) {
        int row = m0 + wm + m * 16 + lg * 4 + r;
        int col = n0 + wn + nf * 16 + l15;
        if (row < Mvalid) {
          float v = acc[m][nf][r] + bias[col];
          out1[(size_t)row * 256 + col] = v * 16.f + out0[(size_t)row * 256 + col];
        }
      }
}

// ---------------- launch ----------------
extern "C" void kernel_launch(void* const* d_in, const int* in_sizes, int n_in,
                              void* d_out, int out_size, void* d_ws, size_t ws_size,
                              hipStream_t stream) {
  const float* x    = (const float*)d_in[0];
  const float* wh   = (const float*)d_in[1];
  const int* ct_ind = (const int*)d_in[2];
  const int* ct_b   = (const int*)d_in[3];
  const float* w1   = (const float*)d_in[4];
  const float* b1   = (const float*)d_in[5];
  const float* w2   = (const float*)d_in[6];
  const float* b2   = (const float*)d_in[7];
  const float* wp   = (const float*)d_in[8];
  const float* wf   = (const float*)d_in[9];
  const float* bfu  = (const float*)d_in[10];
  float* out = (float*)d_out;
  char* ws = (char*)d_ws;

  // ws map (bytes):
  ushort_t* xt       = (ushort_t*)(ws + 0);         // 34,080,768 (4*258*258*64*2)
  ushort_t* partials = (ushort_t*)(ws + 0);         // 16,777,216 bf16 (aliases xt, dead after conv)
  ushort_t* w1t   = (ushort_t*)(ws + 34080768);     //    294,912
  ushort_t* f2    = (ushort_t*)(ws + 34375680);     // 33,554,432
  ushort_t* wpb   = (ushort_t*)(ws + 67930112);     //  8,454,144
  ushort_t* wfb   = (ushort_t*)(ws + 76384256);     //    262,144
  ushort_t* fp    = (ushort_t*)(ws + 76646400);     // 33,024,000 (2000 rows, swizzled)
  ushort_t* off1  = (ushort_t*)(ws + 109670400);    //  2,097,152 (2048x512)
  float*    pts   = (float*)(ws + 111767552);       //  2,064,000  (end 113,831,552)

  cast_xt_kernel<<<dim3(4225), dim3(256), 0, stream>>>(x, xt);
  setup_kernel<<<dim3(3704), dim3(256), 0, stream>>>(w1, w1t, wp, wpb, wf, wfb,
                                                     wh, ct_ind, ct_b, out, pts);
  conv_fused_kernel<<<dim3(1024), dim3(512), 0, stream>>>(xt, w1t, b1, w2, b2, f2);
  sample_kernel<<<dim3(2000), dim3(128), 0, stream>>>(f2, pts, ct_b, fp);
  gemm_splitk_kernel<<<dim3(64, 8), dim3(256), 0, stream>>>(fp, wpb, partials);
  reduce_splitk_kernel<<<dim3(512), dim3(256), 0, stream>>>(partials, off1);
  gemm64_epi_kernel<<<dim3(4, 32), dim3(256), 0, stream>>>(off1, wfb, bfu, out,
                                                           out + 512000, 2000);
}

// Round 12
// 197.765 us; speedup vs baseline: 1.5599x; 1.0118x over previous
//
#include <hip/hip_runtime.h>

typedef unsigned short ushort_t;
typedef __bf16 bf16x8 __attribute__((ext_vector_type(8)));
typedef float f32x4 __attribute__((ext_vector_type(4)));

__device__ __forceinline__ ushort_t f2b(float f) {
  union { float f; unsigned u; } v; v.f = f;
  unsigned r = v.u + 0x7FFFu + ((v.u >> 16) & 1u);
  return (ushort_t)(r >> 16);
}
__device__ __forceinline__ float b2f(ushort_t u) {
  union { unsigned u; float f; } v; v.u = ((unsigned)u) << 16;
  return v.f;
}
__device__ __forceinline__ f32x4 MFMA(bf16x8 a, bf16x8 b, f32x4 c) {
  return __builtin_amdgcn_mfma_f32_16x16x32_bf16(a, b, c, 0, 0, 0);
}
// async global->LDS, 16 B per lane; lds base must be wave-uniform
__device__ __forceinline__ void gload_lds16(const ushort_t* g, ushort_t* l) {
  __builtin_amdgcn_global_load_lds(
      (const __attribute__((address_space(1))) unsigned int*)g,
      (__attribute__((address_space(3))) unsigned int*)l, 16, 0, 0);
}

// xt_pad geometry: [4][258 rows][258 cols][64 ch] bf16, 1-px zero border,
// channel octet stored at slot c ^ ((col&7)<<3)  (pre-swizzled for LDS)
#define XTW 258

// -------- cast cnn_feature NCHW f32 -> padded+swizzled NHWC bf16 (+ border) ------
// grid 4225: blocks <4096 cast; blocks >=4096 zero the border rows/cols.
__global__ void cast_xt_kernel(const float* __restrict__ x, ushort_t* __restrict__ xt) {
  __shared__ float tile[64][65];
  int blk = blockIdx.x;
  int t = threadIdx.x;                // 256
  if (blk >= 4096) {                  // border: 32896 uint4 writes
    int i = (blk - 4096) * 256 + t;
    if (i < 32896) {
      int px_id = i >> 3, oct = (i & 7) << 3;
      int img = px_id / 1028, r = px_id - img * 1028;
      int row, col;
      if (r < 516) { row = (r < 258) ? 0 : 257; col = (r < 258) ? r : r - 258; }
      else { int rr = r - 516; row = 1 + (rr >> 1); col = (rr & 1) ? 257 : 0; }
      uint4 z = make_uint4(0, 0, 0, 0);
      *(uint4*)(xt + (((size_t)img * XTW + row) * XTW + col) * 64 + oct) = z;
    }
    return;
  }
  int b = blk >> 10, rest = blk & 1023;
  int y = rest >> 2, xseg = (rest & 3) << 6;
  int p0 = y * 256 + xseg;
#pragma unroll
  for (int rep = 0; rep < 16; ++rep) {
    int lin = rep * 256 + t;
    int c = lin >> 6, p = lin & 63;
    tile[c][p] = x[((size_t)(b * 64 + c)) * 65536 + p0 + p];
  }
  __syncthreads();
#pragma unroll
  for (int rep = 0; rep < 2; ++rep) {
    int u = rep * 256 + t;            // 512 units of 8ch
    int p = u >> 3, cc = (u & 7) << 3;
    union { ushort_t s[8]; uint4 v; } pk;
#pragma unroll
    for (int j = 0; j < 8; ++j) pk.s[j] = f2b(tile[cc + j][p]);
    int gx = xseg + p + 1;
    size_t base = (((size_t)b * XTW + (y + 1)) * XTW + gx) * 64;
    *(uint4*)(xt + base + (cc ^ ((gx & 7) << 3))) = pk.v;
  }
}

// -------- setup: w1t cast + wpb cast(swz) + wfb cast + prep, fused by blk range ---
// [0,576): w1t  [576,2640): wpb  [2640,2704): wfb  [2704,3704): prep (2 inst/blk)
__global__ void setup_kernel(const float* __restrict__ w1, ushort_t* __restrict__ w1t,
                             const float* __restrict__ wp, ushort_t* __restrict__ wpb,
                             const float* __restrict__ wf, ushort_t* __restrict__ wfb,
                             const float* __restrict__ wh, const int* __restrict__ ct_ind,
                             const int* __restrict__ ct_b, float* __restrict__ out,
                             float* __restrict__ pts) {
  int blk = blockIdx.x, t = threadIdx.x;
  if (blk < 576) {
    int i = blk * 256 + t;            // 147456 total
    int tap = i >> 14;
    int rem = i & 16383;
    int nn = rem >> 6, c = rem & 63;
    int cs = c ^ ((nn & 7) << 3);
    w1t[tap * 16384 + nn * 64 + cs] = f2b(w1[(nn * 64 + c) * 9 + tap]);
  } else if (blk < 2640) {
    for (int i = (blk - 576) * 256 + t; i < 4227072; i += 2064 * 256) {
      int row = i / 8256;
      int col = i - row * 8256;
      wpb[row * 8256 + (col ^ ((row & 7) << 3))] = f2b(wp[i]);
    }
  } else if (blk < 2704) {
    for (int i = (blk - 2640) * 256 + t; i < 131072; i += 64 * 256)
      wfb[i] = f2b(wf[i]);
  } else {
    int n = (blk - 2704) * 2 + (t >> 7);
    int t7 = t & 127;
    int ci = ct_ind[n];
    int b = ct_b[n];
    int ctx = ci & 255;
    int cty = (ci >> 8) & 255;
    float fx = (float)ctx, fy = (float)cty;
    size_t base = ((size_t)b * 256 + 2 * t7) * 65536 + (size_t)cty * 256 + ctx;
    float ox = wh[base];
    float oy = wh[base + 65536];
    float ix = ox * 10.f + fx, iy = oy * 10.f + fy;
    out[(n * 128 + t7) * 2]     = ix * 4.f;
    out[(n * 128 + t7) * 2 + 1] = iy * 4.f;
    float* pn = pts + (size_t)n * 258;
    if (t7 == 0) { pn[0] = fx; pn[1] = fy; }
    pn[2 + t7 * 2] = ix;
    pn[3 + t7 * 2] = iy;
  }
}

// ---------------- fused conv1(3x3)+bias+relu + conv2(1x1)+bias -> f2 NHWC bf16 ----
// 2-row blocks: M=256 px (2 rows x 128), N=256 ch, 8 waves, wave-tile 64x128.
// 4-row strip staged once via async gload_lds; 2-deep LDS weight buffers.
// (Best-measured conv variant; byte-identical to R10/R11.)
__global__ __launch_bounds__(512, 1)
void conv_fused_kernel(const ushort_t* __restrict__ xt, const ushort_t* __restrict__ w1t,
                       const float* __restrict__ b1, const float* __restrict__ w2,
                       const float* __restrict__ b2, ushort_t* __restrict__ f2) {
  __shared__ __align__(16) char smem[163840];
  ushort_t* strip = (ushort_t*)smem;              // [4][136][64] = 69632 B
  ushort_t* Bb0   = (ushort_t*)(smem + 69632);    // [256][64] = 32768 B
  ushort_t* Bb1   = (ushort_t*)(smem + 102400);   // ends 135168
  ushort_t* F1    = (ushort_t*)smem;              // [256][256] = 131072 (epilogue)
  ushort_t* W2l   = (ushort_t*)(smem + 131072);   // [64][256] = 32768 (epilogue)
  ushort_t* T     = (ushort_t*)smem;              // [256][64] (store stage)

  int rawblk = blockIdx.x;                         // 1024
  int blk = ((rawblk & 7) << 7) + (rawblk >> 3);   // bijective XCD swizzle (1024%8==0)
  int b = blk >> 8;
  int rest = blk & 255;
  int y2 = (rest >> 1) << 1;                       // first output row (even)
  int x0 = (rest & 1) << 7;                        // 0 or 128
  int tid = threadIdx.x;
  int wid = tid >> 6, lane = tid & 63;
  int l15 = lane & 15, lg = lane >> 4;
  int wm = (wid >> 1) << 6;    // px offset: 0,64,128,192
  int wn = (wid & 1) << 7;     // ch offset: 0,128

  // prologue: issue weight pf for taps 0,1 (linear dest = pre-swizzled layout)
#pragma unroll
  for (int j = 0; j < 4; ++j) {
    int q = (wid << 2) + j;            // 32 chunks of 1024 B
    gload_lds16(w1t + q * 512 + lane * 8, Bb0 + q * 512);
  }
#pragma unroll
  for (int j = 0; j < 4; ++j) {
    int q = (wid << 2) + j;
    gload_lds16(w1t + 16384 + q * 512 + lane * 8, Bb1 + q * 512);
  }
  // strip: padded rows y2..y2+3, cols x0..x0+135, 68 chunks of 8 px, pure async
  for (int c = wid; c < 68; c += 8) {
    int ry = c / 17, ck = c - ry * 17;
    const ushort_t* g = xt + (((size_t)b * XTW + (y2 + ry)) * XTW + x0 + ck * 8) * 64 + lane * 8;
    gload_lds16(g, strip + (ry * 136 + ck * 8) * 64);
  }
  asm volatile("s_waitcnt vmcnt(0) lgkmcnt(0)" ::: "memory");
  asm volatile("s_barrier" ::: "memory");

  f32x4 acc[4][8] = {};

#pragma unroll
  for (int tap = 0; tap < 9; ++tap) {
    const int dy = tap / 3 - 1, dx = tap % 3 - 1;
    ushort_t* Bcur = (tap & 1) ? Bb1 : Bb0;
    if (tap < 8) {                     // prefetch next tap's weights into the other buf
      ushort_t* Bnxt = (tap & 1) ? Bb0 : Bb1;
      const ushort_t* gb = w1t + (tap + 1) * 16384;
#pragma unroll
      for (int j = 0; j < 4; ++j) {
        int q = (wid << 2) + j;
        gload_lds16(gb + q * 512 + lane * 8, Bnxt + q * 512);
      }
    }
    const int sr  = (wm >> 7) + dy + 1;      // strip row (wave-uniform)
    const int spb = (wm & 127) + dx + 1;     // strip px base
#pragma unroll
    for (int kk = 0; kk < 2; ++kk) {
      int c0 = (kk << 5) + (lg << 3);
      bf16x8 a[4];
#pragma unroll
      for (int m = 0; m < 4; ++m) {
        int sp = spb + m * 16 + l15;
        a[m] = *(const bf16x8*)(strip + ((sr * 136 + sp) << 6) + (c0 ^ ((sp & 7) << 3)));
      }
#pragma unroll
      for (int nf = 0; nf < 8; ++nf) {
        int br = wn + nf * 16 + l15;
        bf16x8 bb = *(const bf16x8*)(Bcur + (br << 6) + (c0 ^ ((br & 7) << 3)));
#pragma unroll
        for (int m = 0; m < 4; ++m)
          acc[m][nf] = MFMA(a[m], bb, acc[m][nf]);
      }
    }
    if (tap < 8) {                     // pf(tap+1) is the only thing outstanding
      asm volatile("s_waitcnt vmcnt(0)" ::: "memory");
      asm volatile("s_barrier" ::: "memory");
    }
  }
  __syncthreads();

  // conv1 epilogue: relu(acc + b1) -> F1 px-major, XOR-swizzled on ch by (p&7)
#pragma unroll
  for (int nf = 0; nf < 8; ++nf) {
    int ch = wn + nf * 16 + l15;
    float bias = b1[ch];
#pragma unroll
    for (int m = 0; m < 4; ++m) {
#pragma unroll
      for (int r = 0; r < 4; ++r) {
        int p = wm + m * 16 + lg * 4 + r;
        F1[(p << 8) + (ch ^ ((p & 7) << 3))] = f2b(fmaxf(acc[m][nf][r] + bias, 0.f));
      }
    }
  }
  // stage w2 (64 oc x 256 ic) -> W2l swizzled on ic by (oc&7)
#pragma unroll
  for (int it = 0; it < 4; ++it) {
    int u = it * 512 + tid;            // 2048 octets
    int oc = u >> 5, ic = (u & 31) << 3;
    float4 fa = *(const float4*)(w2 + (oc << 8) + ic);
    float4 fb = *(const float4*)(w2 + (oc << 8) + ic + 4);
    union { ushort_t s[8]; uint4 v; } pk;
    pk.s[0] = f2b(fa.x); pk.s[1] = f2b(fa.y); pk.s[2] = f2b(fa.z); pk.s[3] = f2b(fa.w);
    pk.s[4] = f2b(fb.x); pk.s[5] = f2b(fb.y); pk.s[6] = f2b(fb.z); pk.s[7] = f2b(fb.w);
    *(uint4*)(W2l + (oc << 8) + (ic ^ ((oc & 7) << 3))) = pk.v;
  }
  __syncthreads();
  // conv2: O[256 px][64 oc] = F1 @ W2^T; wave owns 32 px
  int wpx = wid << 5;
  f32x4 acc2[2][4] = {};
#pragma unroll
  for (int kc = 0; kc < 8; ++kc) {
    int c0 = (kc << 5) + (lg << 3);
    bf16x8 a2[2];
#pragma unroll
    for (int mm = 0; mm < 2; ++mm) {
      int p = wpx + mm * 16 + l15;
      a2[mm] = *(const bf16x8*)(F1 + (p << 8) + (c0 ^ ((p & 7) << 3)));
    }
#pragma unroll
    for (int nf = 0; nf < 4; ++nf) {
      int oc = nf * 16 + l15;
      bf16x8 bw = *(const bf16x8*)(W2l + (oc << 8) + (c0 ^ ((oc & 7) << 3)));
#pragma unroll
      for (int mm = 0; mm < 2; ++mm)
        acc2[mm][nf] = MFMA(a2[mm], bw, acc2[mm][nf]);
    }
  }
  __syncthreads();                     // all F1 reads done; T may overwrite
#pragma unroll
  for (int mm = 0; mm < 2; ++mm)
#pragma unroll
    for (int nf = 0; nf < 4; ++nf) {
      int oc = nf * 16 + l15;
      float bias = b2[oc];
#pragma unroll
      for (int r = 0; r < 4; ++r) {
        int p = wpx + mm * 16 + lg * 4 + r;
        T[(p << 6) + (oc ^ ((p & 7) << 3))] = f2b(acc2[mm][nf][r] + bias);
      }
    }
  __syncthreads();
  const size_t imgbase = (size_t)b * 65536;
#pragma unroll
  for (int it = 0; it < 4; ++it) {
    int u = it * 512 + tid;            // 2048 octets
    int p = u >> 3, co = (u & 7) << 3;
    uint4 v = *(const uint4*)(T + (p << 6) + (co ^ ((p & 7) << 3)));
    int gpx = (y2 + (p >> 7)) * 256 + x0 + (p & 127);
    *(uint4*)(f2 + (imgbase + gpx) * 64 + co) = v;
  }
}

// ---------------- bilinear sample -> fp[n][col ^ swz(n)] bf16 (PRE-SWIZZLED) ------
__global__ void sample_kernel(const ushort_t* __restrict__ f2, const float* __restrict__ pts,
                              const int* __restrict__ ct_b, ushort_t* __restrict__ fp) {
  int n = blockIdx.x, t = threadIdx.x;   // 2000 x 128
  __shared__ float pl[258];
  __shared__ __align__(16) ushort_t fpl[8256];   // [64][129]
  int b = ct_b[n];
  const ushort_t* fb = f2 + (size_t)b * 4194304;
  for (int i = t; i < 258; i += 128) pl[i] = pts[(size_t)n * 258 + i];
  __syncthreads();
  int c4 = t & 15;            // channel quad: ch = 4*c4 .. 4*c4+3
  int ps = t >> 4;            // 0..7 point slot
  for (int base = 0; base < 136; base += 8) {
    int pt = base + ps;
    bool live = pt < 129;
    int ptc = live ? pt : 0;
    float px = pl[ptc * 2], py = pl[ptc * 2 + 1];
    float sx = px - 0.5f, sy = py - 0.5f;
    float fx0 = floorf(sx), fy0 = floorf(sy);
    int x0 = (int)fx0, y0 = (int)fy0;
    float wx1 = sx - fx0, wy1 = sy - fy0;
    float wx0 = 1.f - wx1, wy0 = 1.f - wy1;
    float a0 = 0.f, a1 = 0.f, a2 = 0.f, a3 = 0.f;
#pragma unroll
    for (int cy = 0; cy < 2; ++cy) {
#pragma unroll
      for (int cx = 0; cx < 2; ++cx) {
        int yc = y0 + cy, xc = x0 + cx;
        float w = (cy ? wy1 : wy0) * (cx ? wx1 : wx0);
        bool valid = (xc >= 0) && (xc < 256) && (yc >= 0) && (yc < 256);
        int ycc = min(max(yc, 0), 255), xcc = min(max(xc, 0), 255);
        uint2 v = *(const uint2*)(fb + ((size_t)(ycc * 256 + xcc)) * 64 + (c4 << 2));
        float ww = valid ? w : 0.f;
        a0 += b2f((ushort_t)(v.x & 0xFFFF)) * ww;
        a1 += b2f((ushort_t)(v.x >> 16)) * ww;
        a2 += b2f((ushort_t)(v.y & 0xFFFF)) * ww;
        a3 += b2f((ushort_t)(v.y >> 16)) * ww;
      }
    }
    if (live) {
      int ch = c4 << 2;
      fpl[(ch + 0) * 129 + pt] = f2b(a0);
      fpl[(ch + 1) * 129 + pt] = f2b(a1);
      fpl[(ch + 2) * 129 + pt] = f2b(a2);
      fpl[(ch + 3) * 129 + pt] = f2b(a3);
    }
  }
  __syncthreads();
  uint4* fo = (uint4*)(fp + (size_t)n * 8256);
  const uint4* fi = (const uint4*)fpl;
  int key = n & 7;
  for (int i = t; i < 1032; i += 128) fo[i ^ key] = fi[i];
}

// ---------------- split-K GEMM1: 128x256 tiles, partials[kc][2048][512] BF16 ------
// A = fp (pre-swizzled), B = wpb (pre-swizzled). grid (32 spatial, 8 kc), 512 thr.
// Wider n-tile halves A re-reads (4x -> 2x); XCD map keeps both A panels of an
// XCD's 4 blocks resident in its L2.
__global__ __launch_bounds__(512)
void gemm_splitk_kernel(const ushort_t* __restrict__ A, const ushort_t* __restrict__ B,
                        ushort_t* __restrict__ partials) {
  __shared__ __align__(16) ushort_t Al[8192];    // [128][64] swizzled
  __shared__ __align__(16) ushort_t Bl[16384];   // [256][64] swizzled
  int spatial = blockIdx.x;                      // 32
  int kc = blockIdx.y;                           // 8
  int xcd = spatial & 7, j = spatial >> 3;       // j in [0,4)
  int m_t = (xcd << 1) | (j & 1);                // 0..15
  int n_t = j >> 1;                              // 0..1
  int m0 = m_t << 7, n0 = n_t << 8;
  int ks0 = (129 * kc) >> 3, ks1 = (129 * (kc + 1)) >> 3;   // 64-wide k-steps

  int tid = threadIdx.x;
  int wid = tid >> 6, lane = tid & 63;
  int l15 = lane & 15, lg = lane >> 4;
  int wm = (wid >> 2) << 6;                      // 0,64
  int wn = (wid & 3) << 6;                       // 0,64,128,192
  int srow = (lane >> 3);                        // stage row-in-octet
  int soct = lane & 7;
  f32x4 acc[4][4] = {};
  for (int ks = ks0; ks < ks1; ++ks) {
    __syncthreads();
#pragma unroll
    for (int jj = 0; jj < 6; ++jj) {
      int q = wid + (jj << 3);                   // 48 chunks of 1024 B
      if (q < 16) {                              // A: rows m0+8q..m0+8q+7
        int ar = m0 + (q << 3) + srow;
        if (ar >= 2000) ar = 1992 + (ar & 7);    // clamp, swizzle-key preserved
        gload_lds16(A + (size_t)ar * 8256 + ks * 64 + soct * 8, Al + q * 512);
      } else {                                   // B: rows n0+8(q-16)..
        int br = n0 + ((q - 16) << 3) + srow;
        gload_lds16(B + (size_t)br * 8256 + ks * 64 + soct * 8, Bl + (q - 16) * 512);
      }
    }
    __syncthreads();
#pragma unroll
    for (int kk = 0; kk < 2; ++kk) {
      int c0 = (kk << 5) + (lg << 3);
      bf16x8 a[4], b[4];
#pragma unroll
      for (int m = 0; m < 4; ++m) {
        int row = wm + m * 16 + l15;
        a[m] = *(const bf16x8*)(Al + (row << 6) + (c0 ^ ((row & 7) << 3)));
      }
#pragma unroll
      for (int nf = 0; nf < 4; ++nf) {
        int row = wn + nf * 16 + l15;
        b[nf] = *(const bf16x8*)(Bl + (row << 6) + (c0 ^ ((row & 7) << 3)));
      }
#pragma unroll
      for (int m = 0; m < 4; ++m)
#pragma unroll
        for (int nf = 0; nf < 4; ++nf)
          acc[m][nf] = MFMA(a[m], b[nf], acc[m][nf]);
    }
  }
  ushort_t* pout = partials + (size_t)kc * 1048576;   // 2048*512 bf16
#pragma unroll
  for (int m = 0; m < 4; ++m)
#pragma unroll
    for (int nf = 0; nf < 4; ++nf)
#pragma unroll
      for (int r = 0; r < 4; ++r) {
        int row = m0 + wm + m * 16 + lg * 4 + r;
        int col = n0 + wn + nf * 16 + l15;
        pout[(size_t)row * 512 + col] = f2b(acc[m][nf][r]);
      }
}

// ---------------- reduce 8 bf16 partials -> off1 bf16 [2048][512] ----------------
__global__ void reduce_splitk_kernel(const ushort_t* __restrict__ partials,
                                     ushort_t* __restrict__ off1) {
  int i = blockIdx.x * 256 + threadIdx.x;    // 131072 threads x 8 elems
  size_t idx = (size_t)i * 8;
  float s[8] = {0.f, 0.f, 0.f, 0.f, 0.f, 0.f, 0.f, 0.f};
#pragma unroll
  for (int c = 0; c < 8; ++c) {
    uint4 v = *(const uint4*)(partials + (size_t)c * 1048576 + idx);
    s[0] += b2f((ushort_t)(v.x & 0xFFFF)); s[1] += b2f((ushort_t)(v.x >> 16));
    s[2] += b2f((ushort_t)(v.y & 0xFFFF)); s[3] += b2f((ushort_t)(v.y >> 16));
    s[4] += b2f((ushort_t)(v.z & 0xFFFF)); s[5] += b2f((ushort_t)(v.z >> 16));
    s[6] += b2f((ushort_t)(v.w & 0xFFFF)); s[7] += b2f((ushort_t)(v.w >> 16));
  }
  union { ushort_t u[8]; uint4 v; } pk;
#pragma unroll
  for (int j = 0; j < 8; ++j) pk.u[j] = f2b(s[j]);
  *(uint4*)(off1 + idx) = pk.v;
}

// ---------------- GEMM2: off1 @ wfb^T + bias -> out (64x64 tiles) ----------------
__global__ __launch_bounds__(256)
void gemm64_epi_kernel(const ushort_t* __restrict__ A, const ushort_t* __restrict__ B,
                       const float* __restrict__ bias, const float* __restrict__ out0,
                       float* __restrict__ out1, int Mvalid) {
  __shared__ ushort_t Alds[64][72];
  __shared__ ushort_t Blds[64][72];
  const int K = 512;
  int n0 = blockIdx.x * 64, m0 = blockIdx.y * 64;
  int tid = threadIdx.x;
  int wid = tid >> 6, lane = tid & 63;
  int l15 = lane & 15, lg = lane >> 4;
  int wm = (wid >> 1) * 32, wn = (wid & 1) * 32;
  f32x4 acc[2][2] = {};
  for (int ks = 0; ks < K / 64; ++ks) {
    __syncthreads();
#pragma unroll
    for (int it = 0; it < 2; ++it) {
      int u = it * 256 + tid;
      int r = u >> 3, cc = (u & 7) << 3;
      *(uint4*)(&Alds[r][cc]) = *(const uint4*)(A + (size_t)(m0 + r) * K + ks * 64 + cc);
      *(uint4*)(&Blds[r][cc]) = *(const uint4*)(B + (size_t)(n0 + r) * K + ks * 64 + cc);
    }
    __syncthreads();
#pragma unroll
    for (int kk = 0; kk < 2; ++kk) {
      int c0 = (kk << 5) + (lg << 3);
      bf16x8 a[2], b[2];
      a[0] = *(const bf16x8*)(&Alds[wm + l15][c0]);
      a[1] = *(const bf16x8*)(&Alds[wm + 16 + l15][c0]);
      b[0] = *(const bf16x8*)(&Blds[wn + l15][c0]);
      b[1] = *(const bf16x8*)(&Blds[wn + 16 + l15][c0]);
#pragma unroll
      for (int m = 0; m < 2; ++m)
#pragma unroll
        for (int nf = 0; nf < 2; ++nf)
          acc[m][nf] = MFMA(a[m], b[nf], acc[m][nf]);
    }
  }
#pragma unroll
  for (int m = 0; m < 2; ++m)
#pragma unroll
    for (int nf = 0; nf < 2; ++nf)
#pragma unroll
      for (int r = 0; r < 4; ++r) {
        int row = m0 + wm + m * 16 + lg * 4 + r;
        int col = n0 + wn + nf * 16 + l15;
        if (row < Mvalid) {
          float v = acc[m][nf][r] + bias[col];
          out1[(size_t)row * 256 + col] = v * 16.f + out0[(size_t)row * 256 + col];
        }
      }
}

// ---------------- launch ----------------
extern "C" void kernel_launch(void* const* d_in, const int* in_sizes, int n_in,
                              void* d_out, int out_size, void* d_ws, size_t ws_size,
                              hipStream_t stream) {
  const float* x    = (const float*)d_in[0];
  const float* wh   = (const float*)d_in[1];
  const int* ct_ind = (const int*)d_in[2];
  const int* ct_b   = (const int*)d_in[3];
  const float* w1   = (const float*)d_in[4];
  const float* b1   = (const float*)d_in[5];
  const float* w2   = (const float*)d_in[6];
  const float* b2   = (const float*)d_in[7];
  const float* wp   = (const float*)d_in[8];
  const float* wf   = (const float*)d_in[9];
  const float* bfu  = (const float*)d_in[10];
  float* out = (float*)d_out;
  char* ws = (char*)d_ws;

  // ws map (bytes):
  ushort_t* xt       = (ushort_t*)(ws + 0);         // 34,080,768 (4*258*258*64*2)
  ushort_t* partials = (ushort_t*)(ws + 0);         // 16,777,216 bf16 (aliases xt, dead after conv)
  ushort_t* w1t   = (ushort_t*)(ws + 34080768);     //    294,912
  ushort_t* f2    = (ushort_t*)(ws + 34375680);     // 33,554,432
  ushort_t* wpb   = (ushort_t*)(ws + 67930112);     //  8,454,144
  ushort_t* wfb   = (ushort_t*)(ws + 76384256);     //    262,144
  ushort_t* fp    = (ushort_t*)(ws + 76646400);     // 33,024,000 (2000 rows, swizzled)
  ushort_t* off1  = (ushort_t*)(ws + 109670400);    //  2,097,152 (2048x512)
  float*    pts   = (float*)(ws + 111767552);       //  2,064,000  (end 113,831,552)

  cast_xt_kernel<<<dim3(4225), dim3(256), 0, stream>>>(x, xt);
  setup_kernel<<<dim3(3704), dim3(256), 0, stream>>>(w1, w1t, wp, wpb, wf, wfb,
                                                     wh, ct_ind, ct_b, out, pts);
  conv_fused_kernel<<<dim3(1024), dim3(512), 0, stream>>>(xt, w1t, b1, w2, b2, f2);
  sample_kernel<<<dim3(2000), dim3(128), 0, stream>>>(f2, pts, ct_b, fp);
  gemm_splitk_kernel<<<dim3(32, 8), dim3(512), 0, stream>>>(fp, wpb, partials);
  reduce_splitk_kernel<<<dim3(512), dim3(256), 0, stream>>>(partials, off1);
  gemm64_epi_kernel<<<dim3(4, 32), dim3(256), 0, stream>>>(off1, wfb, bfu, out,
                                                           out + 512000, 2000);
}

// Round 13
// 195.066 us; speedup vs baseline: 1.5815x; 1.0138x over previous
//
#include <hip/hip_runtime.h>

typedef unsigned short ushort_t;
typedef __bf16 bf16x8 __attribute__((ext_vector_type(8)));
typedef float f32x4 __attribute__((ext_vector_type(4)));

__device__ __forceinline__ ushort_t f2b(float f) {
  union { float f; unsigned u; } v; v.f = f;
  unsigned r = v.u + 0x7FFFu + ((v.u >> 16) & 1u);
  return (ushort_t)(r >> 16);
}
__device__ __forceinline__ float b2f(ushort_t u) {
  union { unsigned u; float f; } v; v.u = ((unsigned)u) << 16;
  return v.f;
}
__device__ __forceinline__ f32x4 MFMA(bf16x8 a, bf16x8 b, f32x4 c) {
  return __builtin_amdgcn_mfma_f32_16x16x32_bf16(a, b, c, 0, 0, 0);
}
// async global->LDS, 16 B per lane; lds base must be wave-uniform
__device__ __forceinline__ void gload_lds16(const ushort_t* g, ushort_t* l) {
  __builtin_amdgcn_global_load_lds(
      (const __attribute__((address_space(1))) unsigned int*)g,
      (__attribute__((address_space(3))) unsigned int*)l, 16, 0, 0);
}

// xt_pad geometry: [4][258 rows][258 cols][64 ch] bf16, 1-px zero border,
// channel octet stored at slot c ^ ((col&7)<<3)  (pre-swizzled for LDS)
#define XTW 258

// -------- cast cnn_feature NCHW f32 -> padded+swizzled NHWC bf16 (+ border) ------
// grid 4225: blocks <4096 cast; blocks >=4096 zero the border rows/cols.
__global__ void cast_xt_kernel(const float* __restrict__ x, ushort_t* __restrict__ xt) {
  __shared__ float tile[64][65];
  int blk = blockIdx.x;
  int t = threadIdx.x;                // 256
  if (blk >= 4096) {                  // border: 32896 uint4 writes
    int i = (blk - 4096) * 256 + t;
    if (i < 32896) {
      int px_id = i >> 3, oct = (i & 7) << 3;
      int img = px_id / 1028, r = px_id - img * 1028;
      int row, col;
      if (r < 516) { row = (r < 258) ? 0 : 257; col = (r < 258) ? r : r - 258; }
      else { int rr = r - 516; row = 1 + (rr >> 1); col = (rr & 1) ? 257 : 0; }
      uint4 z = make_uint4(0, 0, 0, 0);
      *(uint4*)(xt + (((size_t)img * XTW + row) * XTW + col) * 64 + oct) = z;
    }
    return;
  }
  int b = blk >> 10, rest = blk & 1023;
  int y = rest >> 2, xseg = (rest & 3) << 6;
  int p0 = y * 256 + xseg;
#pragma unroll
  for (int rep = 0; rep < 16; ++rep) {
    int lin = rep * 256 + t;
    int c = lin >> 6, p = lin & 63;
    tile[c][p] = x[((size_t)(b * 64 + c)) * 65536 + p0 + p];
  }
  __syncthreads();
#pragma unroll
  for (int rep = 0; rep < 2; ++rep) {
    int u = rep * 256 + t;            // 512 units of 8ch
    int p = u >> 3, cc = (u & 7) << 3;
    union { ushort_t s[8]; uint4 v; } pk;
#pragma unroll
    for (int j = 0; j < 8; ++j) pk.s[j] = f2b(tile[cc + j][p]);
    int gx = xseg + p + 1;
    size_t base = (((size_t)b * XTW + (y + 1)) * XTW + gx) * 64;
    *(uint4*)(xt + base + (cc ^ ((gx & 7) << 3))) = pk.v;
  }
}

// -------- setup: w1t cast + wpb cast(swz) + wfb cast + prep, fused by blk range ---
// [0,576): w1t  [576,2640): wpb  [2640,2704): wfb  [2704,3704): prep (2 inst/blk)
__global__ void setup_kernel(const float* __restrict__ w1, ushort_t* __restrict__ w1t,
                             const float* __restrict__ wp, ushort_t* __restrict__ wpb,
                             const float* __restrict__ wf, ushort_t* __restrict__ wfb,
                             const float* __restrict__ wh, const int* __restrict__ ct_ind,
                             const int* __restrict__ ct_b, float* __restrict__ out,
                             float* __restrict__ pts) {
  int blk = blockIdx.x, t = threadIdx.x;
  if (blk < 576) {
    int i = blk * 256 + t;            // 147456 total
    int tap = i >> 14;
    int rem = i & 16383;
    int nn = rem >> 6, c = rem & 63;
    int cs = c ^ ((nn & 7) << 3);
    w1t[tap * 16384 + nn * 64 + cs] = f2b(w1[(nn * 64 + c) * 9 + tap]);
  } else if (blk < 2640) {
    for (int i = (blk - 576) * 256 + t; i < 4227072; i += 2064 * 256) {
      int row = i / 8256;
      int col = i - row * 8256;
      wpb[row * 8256 + (col ^ ((row & 7) << 3))] = f2b(wp[i]);
    }
  } else if (blk < 2704) {
    for (int i = (blk - 2640) * 256 + t; i < 131072; i += 64 * 256)
      wfb[i] = f2b(wf[i]);
  } else {
    int n = (blk - 2704) * 2 + (t >> 7);
    int t7 = t & 127;
    int ci = ct_ind[n];
    int b = ct_b[n];
    int ctx = ci & 255;
    int cty = (ci >> 8) & 255;
    float fx = (float)ctx, fy = (float)cty;
    size_t base = ((size_t)b * 256 + 2 * t7) * 65536 + (size_t)cty * 256 + ctx;
    float ox = wh[base];
    float oy = wh[base + 65536];
    float ix = ox * 10.f + fx, iy = oy * 10.f + fy;
    out[(n * 128 + t7) * 2]     = ix * 4.f;
    out[(n * 128 + t7) * 2 + 1] = iy * 4.f;
    float* pn = pts + (size_t)n * 258;
    if (t7 == 0) { pn[0] = fx; pn[1] = fy; }
    pn[2 + t7 * 2] = ix;
    pn[3 + t7 * 2] = iy;
  }
}

// ---------------- fused conv1(3x3)+bias+relu + conv2(1x1)+bias -> f2 NHWC bf16 ----
// 2-row blocks: M=256 px (2 rows x 128), N=256 ch, 8 waves, wave-tile 64x128.
// 4-row strip staged once via async gload_lds; 2-deep LDS weight buffers.
// (Best-measured conv variant; byte-identical to R10/R11/R12.)
__global__ __launch_bounds__(512, 1)
void conv_fused_kernel(const ushort_t* __restrict__ xt, const ushort_t* __restrict__ w1t,
                       const float* __restrict__ b1, const float* __restrict__ w2,
                       const float* __restrict__ b2, ushort_t* __restrict__ f2) {
  __shared__ __align__(16) char smem[163840];
  ushort_t* strip = (ushort_t*)smem;              // [4][136][64] = 69632 B
  ushort_t* Bb0   = (ushort_t*)(smem + 69632);    // [256][64] = 32768 B
  ushort_t* Bb1   = (ushort_t*)(smem + 102400);   // ends 135168
  ushort_t* F1    = (ushort_t*)smem;              // [256][256] = 131072 (epilogue)
  ushort_t* W2l   = (ushort_t*)(smem + 131072);   // [64][256] = 32768 (epilogue)
  ushort_t* T     = (ushort_t*)smem;              // [256][64] (store stage)

  int rawblk = blockIdx.x;                         // 1024
  int blk = ((rawblk & 7) << 7) + (rawblk >> 3);   // bijective XCD swizzle (1024%8==0)
  int b = blk >> 8;
  int rest = blk & 255;
  int y2 = (rest >> 1) << 1;                       // first output row (even)
  int x0 = (rest & 1) << 7;                        // 0 or 128
  int tid = threadIdx.x;
  int wid = tid >> 6, lane = tid & 63;
  int l15 = lane & 15, lg = lane >> 4;
  int wm = (wid >> 1) << 6;    // px offset: 0,64,128,192
  int wn = (wid & 1) << 7;     // ch offset: 0,128

  // prologue: issue weight pf for taps 0,1 (linear dest = pre-swizzled layout)
#pragma unroll
  for (int j = 0; j < 4; ++j) {
    int q = (wid << 2) + j;            // 32 chunks of 1024 B
    gload_lds16(w1t + q * 512 + lane * 8, Bb0 + q * 512);
  }
#pragma unroll
  for (int j = 0; j < 4; ++j) {
    int q = (wid << 2) + j;
    gload_lds16(w1t + 16384 + q * 512 + lane * 8, Bb1 + q * 512);
  }
  // strip: padded rows y2..y2+3, cols x0..x0+135, 68 chunks of 8 px, pure async
  for (int c = wid; c < 68; c += 8) {
    int ry = c / 17, ck = c - ry * 17;
    const ushort_t* g = xt + (((size_t)b * XTW + (y2 + ry)) * XTW + x0 + ck * 8) * 64 + lane * 8;
    gload_lds16(g, strip + (ry * 136 + ck * 8) * 64);
  }
  asm volatile("s_waitcnt vmcnt(0) lgkmcnt(0)" ::: "memory");
  asm volatile("s_barrier" ::: "memory");

  f32x4 acc[4][8] = {};

#pragma unroll
  for (int tap = 0; tap < 9; ++tap) {
    const int dy = tap / 3 - 1, dx = tap % 3 - 1;
    ushort_t* Bcur = (tap & 1) ? Bb1 : Bb0;
    if (tap < 8) {                     // prefetch next tap's weights into the other buf
      ushort_t* Bnxt = (tap & 1) ? Bb0 : Bb1;
      const ushort_t* gb = w1t + (tap + 1) * 16384;
#pragma unroll
      for (int j = 0; j < 4; ++j) {
        int q = (wid << 2) + j;
        gload_lds16(gb + q * 512 + lane * 8, Bnxt + q * 512);
      }
    }
    const int sr  = (wm >> 7) + dy + 1;      // strip row (wave-uniform)
    const int spb = (wm & 127) + dx + 1;     // strip px base
#pragma unroll
    for (int kk = 0; kk < 2; ++kk) {
      int c0 = (kk << 5) + (lg << 3);
      bf16x8 a[4];
#pragma unroll
      for (int m = 0; m < 4; ++m) {
        int sp = spb + m * 16 + l15;
        a[m] = *(const bf16x8*)(strip + ((sr * 136 + sp) << 6) + (c0 ^ ((sp & 7) << 3)));
      }
#pragma unroll
      for (int nf = 0; nf < 8; ++nf) {
        int br = wn + nf * 16 + l15;
        bf16x8 bb = *(const bf16x8*)(Bcur + (br << 6) + (c0 ^ ((br & 7) << 3)));
#pragma unroll
        for (int m = 0; m < 4; ++m)
          acc[m][nf] = MFMA(a[m], bb, acc[m][nf]);
      }
    }
    if (tap < 8) {                     // pf(tap+1) is the only thing outstanding
      asm volatile("s_waitcnt vmcnt(0)" ::: "memory");
      asm volatile("s_barrier" ::: "memory");
    }
  }
  __syncthreads();

  // conv1 epilogue: relu(acc + b1) -> F1 px-major, XOR-swizzled on ch by (p&7)
#pragma unroll
  for (int nf = 0; nf < 8; ++nf) {
    int ch = wn + nf * 16 + l15;
    float bias = b1[ch];
#pragma unroll
    for (int m = 0; m < 4; ++m) {
#pragma unroll
      for (int r = 0; r < 4; ++r) {
        int p = wm + m * 16 + lg * 4 + r;
        F1[(p << 8) + (ch ^ ((p & 7) << 3))] = f2b(fmaxf(acc[m][nf][r] + bias, 0.f));
      }
    }
  }
  // stage w2 (64 oc x 256 ic) -> W2l swizzled on ic by (oc&7)
#pragma unroll
  for (int it = 0; it < 4; ++it) {
    int u = it * 512 + tid;            // 2048 octets
    int oc = u >> 5, ic = (u & 31) << 3;
    float4 fa = *(const float4*)(w2 + (oc << 8) + ic);
    float4 fb = *(const float4*)(w2 + (oc << 8) + ic + 4);
    union { ushort_t s[8]; uint4 v; } pk;
    pk.s[0] = f2b(fa.x); pk.s[1] = f2b(fa.y); pk.s[2] = f2b(fa.z); pk.s[3] = f2b(fa.w);
    pk.s[4] = f2b(fb.x); pk.s[5] = f2b(fb.y); pk.s[6] = f2b(fb.z); pk.s[7] = f2b(fb.w);
    *(uint4*)(W2l + (oc << 8) + (ic ^ ((oc & 7) << 3))) = pk.v;
  }
  __syncthreads();
  // conv2: O[256 px][64 oc] = F1 @ W2^T; wave owns 32 px
  int wpx = wid << 5;
  f32x4 acc2[2][4] = {};
#pragma unroll
  for (int kc = 0; kc < 8; ++kc) {
    int c0 = (kc << 5) + (lg << 3);
    bf16x8 a2[2];
#pragma unroll
    for (int mm = 0; mm < 2; ++mm) {
      int p = wpx + mm * 16 + l15;
      a2[mm] = *(const bf16x8*)(F1 + (p << 8) + (c0 ^ ((p & 7) << 3)));
    }
#pragma unroll
    for (int nf = 0; nf < 4; ++nf) {
      int oc = nf * 16 + l15;
      bf16x8 bw = *(const bf16x8*)(W2l + (oc << 8) + (c0 ^ ((oc & 7) << 3)));
#pragma unroll
      for (int mm = 0; mm < 2; ++mm)
        acc2[mm][nf] = MFMA(a2[mm], bw, acc2[mm][nf]);
    }
  }
  __syncthreads();                     // all F1 reads done; T may overwrite
#pragma unroll
  for (int mm = 0; mm < 2; ++mm)
#pragma unroll
    for (int nf = 0; nf < 4; ++nf) {
      int oc = nf * 16 + l15;
      float bias = b2[oc];
#pragma unroll
      for (int r = 0; r < 4; ++r) {
        int p = wpx + mm * 16 + lg * 4 + r;
        T[(p << 6) + (oc ^ ((p & 7) << 3))] = f2b(acc2[mm][nf][r] + bias);
      }
    }
  __syncthreads();
  const size_t imgbase = (size_t)b * 65536;
#pragma unroll
  for (int it = 0; it < 4; ++it) {
    int u = it * 512 + tid;            // 2048 octets
    int p = u >> 3, co = (u & 7) << 3;
    uint4 v = *(const uint4*)(T + (p << 6) + (co ^ ((p & 7) << 3)));
    int gpx = (y2 + (p >> 7)) * 256 + x0 + (p & 127);
    *(uint4*)(f2 + (imgbase + gpx) * 64 + co) = v;
  }
}

// ---------------- bilinear sample -> fp[n][col ^ swz(n)] bf16 (PRE-SWIZZLED) ------
__global__ void sample_kernel(const ushort_t* __restrict__ f2, const float* __restrict__ pts,
                              const int* __restrict__ ct_b, ushort_t* __restrict__ fp) {
  int n = blockIdx.x, t = threadIdx.x;   // 2000 x 128
  __shared__ float pl[258];
  __shared__ __align__(16) ushort_t fpl[8256];   // [64][129]
  int b = ct_b[n];
  const ushort_t* fb = f2 + (size_t)b * 4194304;
  for (int i = t; i < 258; i += 128) pl[i] = pts[(size_t)n * 258 + i];
  __syncthreads();
  int c4 = t & 15;            // channel quad: ch = 4*c4 .. 4*c4+3
  int ps = t >> 4;            // 0..7 point slot
  for (int base = 0; base < 136; base += 8) {
    int pt = base + ps;
    bool live = pt < 129;
    int ptc = live ? pt : 0;
    float px = pl[ptc * 2], py = pl[ptc * 2 + 1];
    float sx = px - 0.5f, sy = py - 0.5f;
    float fx0 = floorf(sx), fy0 = floorf(sy);
    int x0 = (int)fx0, y0 = (int)fy0;
    float wx1 = sx - fx0, wy1 = sy - fy0;
    float wx0 = 1.f - wx1, wy0 = 1.f - wy1;
    float a0 = 0.f, a1 = 0.f, a2 = 0.f, a3 = 0.f;
#pragma unroll
    for (int cy = 0; cy < 2; ++cy) {
#pragma unroll
      for (int cx = 0; cx < 2; ++cx) {
        int yc = y0 + cy, xc = x0 + cx;
        float w = (cy ? wy1 : wy0) * (cx ? wx1 : wx0);
        bool valid = (xc >= 0) && (xc < 256) && (yc >= 0) && (yc < 256);
        int ycc = min(max(yc, 0), 255), xcc = min(max(xc, 0), 255);
        uint2 v = *(const uint2*)(fb + ((size_t)(ycc * 256 + xcc)) * 64 + (c4 << 2));
        float ww = valid ? w : 0.f;
        a0 += b2f((ushort_t)(v.x & 0xFFFF)) * ww;
        a1 += b2f((ushort_t)(v.x >> 16)) * ww;
        a2 += b2f((ushort_t)(v.y & 0xFFFF)) * ww;
        a3 += b2f((ushort_t)(v.y >> 16)) * ww;
      }
    }
    if (live) {
      int ch = c4 << 2;
      fpl[(ch + 0) * 129 + pt] = f2b(a0);
      fpl[(ch + 1) * 129 + pt] = f2b(a1);
      fpl[(ch + 2) * 129 + pt] = f2b(a2);
      fpl[(ch + 3) * 129 + pt] = f2b(a3);
    }
  }
  __syncthreads();
  uint4* fo = (uint4*)(fp + (size_t)n * 8256);
  const uint4* fi = (const uint4*)fpl;
  int key = n & 7;
  for (int i = t; i < 1032; i += 128) fo[i ^ key] = fi[i];
}

// ---------------- split-K GEMM1: 128x256 tiles, partials[kc][2048][512] BF16 ------
// A = fp (pre-swizzled), B = wpb (pre-swizzled). grid (32 spatial, 8 kc), 512 thr.
__global__ __launch_bounds__(512)
void gemm_splitk_kernel(const ushort_t* __restrict__ A, const ushort_t* __restrict__ B,
                        ushort_t* __restrict__ partials) {
  __shared__ __align__(16) ushort_t Al[8192];    // [128][64] swizzled
  __shared__ __align__(16) ushort_t Bl[16384];   // [256][64] swizzled
  int spatial = blockIdx.x;                      // 32
  int kc = blockIdx.y;                           // 8
  int xcd = spatial & 7, j = spatial >> 3;       // j in [0,4)
  int m_t = (xcd << 1) | (j & 1);                // 0..15
  int n_t = j >> 1;                              // 0..1
  int m0 = m_t << 7, n0 = n_t << 8;
  int ks0 = (129 * kc) >> 3, ks1 = (129 * (kc + 1)) >> 3;   // 64-wide k-steps

  int tid = threadIdx.x;
  int wid = tid >> 6, lane = tid & 63;
  int l15 = lane & 15, lg = lane >> 4;
  int wm = (wid >> 2) << 6;                      // 0,64
  int wn = (wid & 3) << 6;                       // 0,64,128,192
  int srow = (lane >> 3);                        // stage row-in-octet
  int soct = lane & 7;
  f32x4 acc[4][4] = {};
  for (int ks = ks0; ks < ks1; ++ks) {
    __syncthreads();
#pragma unroll
    for (int jj = 0; jj < 6; ++jj) {
      int q = wid + (jj << 3);                   // 48 chunks of 1024 B
      if (q < 16) {                              // A: rows m0+8q..m0+8q+7
        int ar = m0 + (q << 3) + srow;
        if (ar >= 2000) ar = 1992 + (ar & 7);    // clamp, swizzle-key preserved
        gload_lds16(A + (size_t)ar * 8256 + ks * 64 + soct * 8, Al + q * 512);
      } else {                                   // B: rows n0+8(q-16)..
        int br = n0 + ((q - 16) << 3) + srow;
        gload_lds16(B + (size_t)br * 8256 + ks * 64 + soct * 8, Bl + (q - 16) * 512);
      }
    }
    __syncthreads();
#pragma unroll
    for (int kk = 0; kk < 2; ++kk) {
      int c0 = (kk << 5) + (lg << 3);
      bf16x8 a[4], b[4];
#pragma unroll
      for (int m = 0; m < 4; ++m) {
        int row = wm + m * 16 + l15;
        a[m] = *(const bf16x8*)(Al + (row << 6) + (c0 ^ ((row & 7) << 3)));
      }
#pragma unroll
      for (int nf = 0; nf < 4; ++nf) {
        int row = wn + nf * 16 + l15;
        b[nf] = *(const bf16x8*)(Bl + (row << 6) + (c0 ^ ((row & 7) << 3)));
      }
#pragma unroll
      for (int m = 0; m < 4; ++m)
#pragma unroll
        for (int nf = 0; nf < 4; ++nf)
          acc[m][nf] = MFMA(a[m], b[nf], acc[m][nf]);
    }
  }
  ushort_t* pout = partials + (size_t)kc * 1048576;   // 2048*512 bf16
#pragma unroll
  for (int m = 0; m < 4; ++m)
#pragma unroll
    for (int nf = 0; nf < 4; ++nf)
#pragma unroll
      for (int r = 0; r < 4; ++r) {
        int row = m0 + wm + m * 16 + lg * 4 + r;
        int col = n0 + wn + nf * 16 + l15;
        pout[(size_t)row * 512 + col] = f2b(acc[m][nf][r]);
      }
}

// -------- GEMM2 fused with split-K reduce: out1 = (sum_kc(partials) @ wfb^T + b)*16 + out0
// grid 64: 32 m-tiles x 2 n-halves; 512 thr, 8 waves, wave-tile 32x32.
// A-tile staged by summing the 8 bf16 partials in f32, repacked to bf16 (same
// numerics as the old reduce kernel). B = wfb [256][512] bf16 row-major.
__global__ __launch_bounds__(512)
void gemm2_fused_kernel(const ushort_t* __restrict__ partials, const ushort_t* __restrict__ B,
                        const float* __restrict__ bias, const float* __restrict__ out0,
                        float* __restrict__ out1) {
  __shared__ ushort_t Alds[64][72];
  __shared__ ushort_t Blds[128][72];
  int m0 = (blockIdx.x >> 1) * 64;
  int n0 = (blockIdx.x & 1) * 128;
  int tid = threadIdx.x;
  int wid = tid >> 6, lane = tid & 63;
  int l15 = lane & 15, lg = lane >> 4;
  int wm = (wid >> 2) * 32;            // 0,32
  int wn = (wid & 3) * 32;             // 0,32,64,96
  f32x4 acc[2][2] = {};
  for (int ks = 0; ks < 8; ++ks) {
    __syncthreads();
    // A: 64 rows x 64 k, one octet per thread, summed over the 8 partials
    {
      int r = tid >> 3, oc = (tid & 7) << 3;
      size_t base = (size_t)(m0 + r) * 512 + ks * 64 + oc;
      float s[8] = {0.f, 0.f, 0.f, 0.f, 0.f, 0.f, 0.f, 0.f};
#pragma unroll
      for (int c = 0; c < 8; ++c) {
        uint4 v = *(const uint4*)(partials + (size_t)c * 1048576 + base);
        s[0] += b2f((ushort_t)(v.x & 0xFFFF)); s[1] += b2f((ushort_t)(v.x >> 16));
        s[2] += b2f((ushort_t)(v.y & 0xFFFF)); s[3] += b2f((ushort_t)(v.y >> 16));
        s[4] += b2f((ushort_t)(v.z & 0xFFFF)); s[5] += b2f((ushort_t)(v.z >> 16));
        s[6] += b2f((ushort_t)(v.w & 0xFFFF)); s[7] += b2f((ushort_t)(v.w >> 16));
      }
      union { ushort_t u[8]; uint4 v; } pk;
#pragma unroll
      for (int jj = 0; jj < 8; ++jj) pk.u[jj] = f2b(s[jj]);
      *(uint4*)(&Alds[r][oc]) = pk.v;
    }
    // B: 128 rows x 64 k, 1024 octets, 2 per thread
#pragma unroll
    for (int it = 0; it < 2; ++it) {
      int u = it * 512 + tid;
      int r = u >> 3, oc = (u & 7) << 3;
      *(uint4*)(&Blds[r][oc]) = *(const uint4*)(B + (size_t)(n0 + r) * 512 + ks * 64 + oc);
    }
    __syncthreads();
#pragma unroll
    for (int kk = 0; kk < 2; ++kk) {
      int c0 = (kk << 5) + (lg << 3);
      bf16x8 a[2], b[2];
      a[0] = *(const bf16x8*)(&Alds[wm + l15][c0]);
      a[1] = *(const bf16x8*)(&Alds[wm + 16 + l15][c0]);
      b[0] = *(const bf16x8*)(&Blds[wn + l15][c0]);
      b[1] = *(const bf16x8*)(&Blds[wn + 16 + l15][c0]);
#pragma unroll
      for (int m = 0; m < 2; ++m)
#pragma unroll
        for (int nf = 0; nf < 2; ++nf)
          acc[m][nf] = MFMA(a[m], b[nf], acc[m][nf]);
    }
  }
#pragma unroll
  for (int m = 0; m < 2; ++m)
#pragma unroll
    for (int nf = 0; nf < 2; ++nf)
#pragma unroll
      for (int r = 0; r < 4; ++r) {
        int row = m0 + wm + m * 16 + lg * 4 + r;
        int col = n0 + wn + nf * 16 + l15;
        if (row < 2000) {
          float v = acc[m][nf][r] + bias[col];
          out1[(size_t)row * 256 + col] = v * 16.f + out0[(size_t)row * 256 + col];
        }
      }
}

// ---------------- launch ----------------
extern "C" void kernel_launch(void* const* d_in, const int* in_sizes, int n_in,
                              void* d_out, int out_size, void* d_ws, size_t ws_size,
                              hipStream_t stream) {
  const float* x    = (const float*)d_in[0];
  const float* wh   = (const float*)d_in[1];
  const int* ct_ind = (const int*)d_in[2];
  const int* ct_b   = (const int*)d_in[3];
  const float* w1   = (const float*)d_in[4];
  const float* b1   = (const float*)d_in[5];
  const float* w2   = (const float*)d_in[6];
  const float* b2   = (const float*)d_in[7];
  const float* wp   = (const float*)d_in[8];
  const float* wf   = (const float*)d_in[9];
  const float* bfu  = (const float*)d_in[10];
  float* out = (float*)d_out;
  char* ws = (char*)d_ws;

  // ws map (bytes):
  ushort_t* xt       = (ushort_t*)(ws + 0);         // 34,080,768 (4*258*258*64*2)
  ushort_t* partials = (ushort_t*)(ws + 0);         // 16,777,216 bf16 (aliases xt, dead after conv)
  ushort_t* w1t   = (ushort_t*)(ws + 34080768);     //    294,912
  ushort_t* f2    = (ushort_t*)(ws + 34375680);     // 33,554,432
  ushort_t* wpb   = (ushort_t*)(ws + 67930112);     //  8,454,144
  ushort_t* wfb   = (ushort_t*)(ws + 76384256);     //    262,144
  ushort_t* fp    = (ushort_t*)(ws + 76646400);     // 33,024,000 (2000 rows, swizzled)
  float*    pts   = (float*)(ws + 111767552);       //  2,064,000  (end 113,831,552)

  cast_xt_kernel<<<dim3(4225), dim3(256), 0, stream>>>(x, xt);
  setup_kernel<<<dim3(3704), dim3(256), 0, stream>>>(w1, w1t, wp, wpb, wf, wfb,
                                                     wh, ct_ind, ct_b, out, pts);
  conv_fused_kernel<<<dim3(1024), dim3(512), 0, stream>>>(xt, w1t, b1, w2, b2, f2);
  sample_kernel<<<dim3(2000), dim3(128), 0, stream>>>(f2, pts, ct_b, fp);
  gemm_splitk_kernel<<<dim3(32, 8), dim3(512), 0, stream>>>(fp, wpb, partials);
  gemm2_fused_kernel<<<dim3(64), dim3(512), 0, stream>>>(partials, wfb, bfu, out,
                                                         out + 512000);
}